// Round 16
// baseline (798.128 us; speedup 1.0000x reference)
//
#include <hip/hip_runtime.h>
#include <hip/hip_fp16.h>
#include <math.h>

#define NTRAIN 2000
#define DIMD 210
#define DIMI 63
#define NPERM 12
#define NCOLS 8
#define NATOM 21
#define SIGF 10.0f

// ws layout (ints):
#define WS_PERM      0        // 2520
#define WS_PAIRROW   5040     // 210
#define WS_PAIRCOL   5250     // 210
#define WS_GTAB      6300     // 5040
#define WS_ENTOFF    11340    // 442
#define WS_ENTS      11782    // 10080
#define WS_TILEMAP   21862    // 441
#define WS_PERMAB    22304    // 2520 (ends 24824)
#define WS_AOFF      24832    // 2206 (cell-pair CSR offsets)
#define WS_AENTS     27040    // 5040 (ends 32080)
#define A_INT_OFF    32768
#define A_BYTE_OFF   (A_INT_OFF * 4)
#define A_PER_N      (64 * 224)
#define A_BYTES      ((size_t)NTRAIN * A_PER_N * 2)
#define WS_NEEDED    ((size_t)A_BYTE_OFF + A_BYTES)

typedef _Float16 f16x8 __attribute__((ext_vector_type(8)));
typedef float f32x4 __attribute__((ext_vector_type(4)));

// ---------------- setup ----------------
__global__ __launch_bounds__(512) void gdml_setup(const int* __restrict__ tril,
                                                  int* __restrict__ ws, int wsBig) {
  __shared__ int sPerm[NPERM * DIMD];
  __shared__ int sInv[NPERM * DIMD];
  __shared__ int sRow[DIMD], sCol[DIMD];
  __shared__ int sPairs[NATOM * 20], sNeg[NATOM * 20];
  __shared__ int sCnt[441];
  __shared__ int sScan[512];
  __shared__ int sOff[442];
  __shared__ int sACnt[2205];

  const int tid = threadIdx.x;

  for (int d = tid; d < DIMD; d += 512) {
    int a = 1;
    while ((a * (a + 1)) / 2 <= d) a++;
    sRow[d] = a;
    sCol[d] = d - (a * (a - 1)) / 2;
  }
  for (int idx = tid; idx < NPERM * DIMD; idx += 512) {
    int p = idx / DIMD, d = idx % DIMD;
    sPerm[idx] = tril[d * NPERM + p] % DIMD;
  }
  __syncthreads();
  for (int idx = tid; idx < NPERM * DIMD; idx += 512) {
    int p = idx / DIMD;
    sInv[p * DIMD + sPerm[idx]] = idx % DIMD;
  }
  if (tid < NATOM) {
    int t = tid, c = 0;
    for (int d = 0; d < DIMD; ++d) {
      if (sRow[d] == t)      { sPairs[t * 20 + c] = d; sNeg[t * 20 + c] = 0; c++; }
      else if (sCol[d] == t) { sPairs[t * 20 + c] = d; sNeg[t * 20 + c] = 1; c++; }
    }
  }
  __syncthreads();

  for (int idx = tid; idx < NPERM * DIMD; idx += 512) ws[WS_PERM + idx] = sPerm[idx];
  for (int d = tid; d < DIMD; d += 512) {
    ws[WS_PAIRROW + d] = sRow[d];
    ws[WS_PAIRCOL + d] = sCol[d];
  }
  // gtab[(p*21+at)*20+i] = d | tw<<9 | pd<<18 | neg<<27
  for (int idx = tid; idx < NPERM * NATOM * 20; idx += 512) {
    int p = idx / (NATOM * 20);
    int r = idx % (NATOM * 20);
    int d = sPairs[r], neg = sNeg[r];
    int tw = sInv[p * DIMD + d];
    int pd = sPerm[p * DIMD + d];
    ws[WS_GTAB + idx] = d | (tw << 9) | (pd << 18) | (neg << 27);
  }
  if (wsBig) {
    for (int idx = tid; idx < NPERM * DIMD; idx += 512) {
      int dd = sPerm[idx];
      ws[WS_PERMAB + idx] = dd | (sRow[dd] << 8) | (sCol[dd] << 13);
    }
  }

  // ---- cell-pair CSR for MFMA M-build: item w=(a, kp); k=invperm[p][dd], kp=k>>1 ----
  for (int w = tid; w < 2205; w += 512) {
    int a = w / 105, kp = w - a * 105, c = 0;
    for (int i = 0; i < 20; ++i) {
      int dd = sPairs[a * 20 + i];
      for (int p = 0; p < NPERM; ++p)
        c += ((sInv[p * DIMD + dd] >> 1) == kp);
    }
    sACnt[w] = c;
  }
  __syncthreads();
  // two-level scan: 441 chunks of 5
  {
    int s = 0;
    if (tid < 441) {
      int lo = tid * 5;
      for (int w = lo; w < lo + 5; ++w) s += sACnt[w];
    }
    sScan[tid] = (tid < 441) ? s : 0;
  }
  __syncthreads();
  for (int s = 1; s < 512; s <<= 1) {
    int v = (tid >= s) ? sScan[tid - s] : 0;
    __syncthreads();
    sScan[tid] += v;
    __syncthreads();
  }
  if (tid < 441) {
    int o = (tid == 0) ? 0 : sScan[tid - 1];
    int lo = tid * 5;
    for (int w = lo; w < lo + 5; ++w) { ws[WS_AOFF + w] = o; o += sACnt[w]; }
  }
  if (tid == 0) ws[WS_AOFF + 2205] = sScan[440];
  __syncthreads();
  // fill: ent = dd | p<<9 | kparity<<13 | negbit<<14  (negbit = negA^1)
  for (int w = tid; w < 2205; w += 512) {
    int a = w / 105, kp = w - a * 105;
    int o = ws[WS_AOFF + w];
    for (int i = 0; i < 20; ++i) {
      int dd = sPairs[a * 20 + i], negA = sNeg[a * 20 + i];
      for (int p = 0; p < NPERM; ++p) {
        int k = sInv[p * DIMD + dd];
        if ((k >> 1) == kp)
          ws[WS_AENTS + (o++)] = dd | (p << 9) | ((k & 1) << 13) | ((negA ^ 1) << 14);
      }
    }
  }

  // ---- fallback-path CSR (unchanged, R12) ----
  for (int q = tid; q < 441; q += 512) {
    int A = q / NATOM, B = q % NATOM, c = 0;
    for (int i = 0; i < 20; ++i) {
      int d = sPairs[A * 20 + i];
      for (int p = 0; p < NPERM; ++p) {
        int dd = sPerm[p * DIMD + d];
        c += (sRow[dd] == B) + (sCol[dd] == B);
      }
    }
    sCnt[q] = c;
  }
  __syncthreads();
  sScan[tid] = (tid < 441) ? sCnt[tid] : 0;
  __syncthreads();
  for (int s = 1; s < 512; s <<= 1) {
    int v = (tid >= s) ? sScan[tid - s] : 0;
    __syncthreads();
    sScan[tid] += v;
    __syncthreads();
  }
  if (tid == 0) sOff[0] = 0;
  if (tid < 441) sOff[tid + 1] = sScan[tid];
  __syncthreads();
  for (int q = tid; q < 442; q += 512) ws[WS_ENTOFF + q] = sOff[q];
  for (int q = tid; q < 441; q += 512) {
    int c = sCnt[q], r = 0;
    for (int q2 = 0; q2 < 441; ++q2) {
      int c2v = sCnt[q2];
      r += (c2v > c) || (c2v == c && q2 < q);
    }
    ws[WS_TILEMAP + r] = q;
  }
  for (int q = tid; q < 441; q += 512) {
    int A = q / NATOM, B = q % NATOM;
    int o = sOff[q];
    for (int i = 0; i < 20; ++i) {
      int d = sPairs[A * 20 + i];
      int negA = sNeg[A * 20 + i];
      for (int p = 0; p < NPERM; ++p) {
        int dd = sPerm[p * DIMD + d];
        int base = (d << 3) | (dd << 15) | (p << 26);
        if (sRow[dd] == B) ws[WS_ENTS + (o++)] = base | ((negA ^ 1) << 30);
        if (sCol[dd] == B) ws[WS_ENTS + (o++)] = base | (negA << 30);
      }
    }
  }
}

// -------- build A_n = RdnFull^T (fp16 [64][224]) — sparse fill --------
__global__ __launch_bounds__(256) void build_A(const float* __restrict__ R_d_desc,
                                               int* __restrict__ ws) {
  const int bid = blockIdx.x;
  const int n = (bid & 7) * (NTRAIN / 8) + (bid >> 3);
  const int* gtab = ws + WS_GTAB;
  _Float16* A = (_Float16*)((char*)ws + A_BYTE_OFF) + (size_t)n * A_PER_N;
  const float* rd = R_d_desc + (size_t)n * (DIMD * 3);
  const int tid = threadIdx.x;

  f16x8 z = {0, 0, 0, 0, 0, 0, 0, 0};
  for (int u = tid; u < 64 * 28; u += 256) ((f16x8*)A)[u] = z;
  __syncthreads();

  for (int u = tid; u < NATOM * 20; u += 256) {
    int v = gtab[u];
    int d = v & 511;
    float s = (v & (1 << 27)) ? -1.0f : 1.0f;
    int at = u / 20;
    A[(3 * at + 0) * 224 + d] = (_Float16)(s * rd[3 * d + 0]);
    A[(3 * at + 1) * 224 + d] = (_Float16)(s * rd[3 * d + 1]);
    A[(3 * at + 2) * 224 + d] = (_Float16)(s * rd[3 * d + 2]);
  }
}

__device__ inline unsigned h16(float f) {
  return (unsigned)__half_as_ushort(__float2half_rn(f));
}
__device__ inline float uh(unsigned u) {
  return __half2float(__ushort_as_half((unsigned short)(u & 0xFFFFu)));
}
__device__ inline int tswz(int r, int e) {
  return r * 64 + ((((e >> 3) ^ r) & 7) << 3) + (e & 7);
}
__device__ inline float pick3(uint2 v, int u) {
  return (u == 0) ? uh(v.x) : (u == 1) ? uh(v.x >> 16) : uh(v.y);
}
// fragment-major half-index for B operand: e=col (0..63), k (0..223)
__device__ inline int fidx(int e, int k) {
  return (e >> 4) * 3584 + (k >> 5) * 512 + (((k >> 3) & 3) << 7) + ((e & 15) << 3) + (k & 7);
}

// ---------------- MFMA main ----------------
__global__ __launch_bounds__(256, 4) void gdml_main_mfma(
    const float* __restrict__ R_desc, const float* __restrict__ R_d_desc,
    const int* __restrict__ j_idxs, const int* __restrict__ ws,
    float* __restrict__ out) {
  const int* perm  = ws + WS_PERM;
  const int* gtab  = ws + WS_GTAB;
  const int* aOff  = ws + WS_AOFF;
  const int* aEnts = ws + WS_AENTS;

  const int bid = blockIdx.x;
  const int x = bid & 7;
  const int t = bid >> 3;
  const int n = x * (NTRAIN / 8) + (t >> 3);   // XCD-affinity
  const int jc = t & 7;
  const int tid = threadIdx.x;
  const int j = j_idxs[jc];

  // BF: fragment-major B operand [4nt][7kk][4kOct][16ci][8] fp16 (28,672B);
  // tileH (8,064B) aliases it after the MFMA barrier.
  __shared__ __align__(16) char uniBF[4 * 3584 * 2];
  _Float16* BF = (_Float16*)uniBF;
  ushort* tileH = (ushort*)uniBF;
  __shared__ uint2 Rdn2[DIMD];                        // 1,680
  __shared__ uint2 Rdj2[DIMD];                        // 1,680
  __shared__ __align__(16) _Float16 Gk[64][16];       // 2,048
  __shared__ float c1s[NPERM], c2s[NPERM];            // 96
  __shared__ float Rn[DIMD], Rj[DIMD];                // 1,680
  __shared__ float partial[252];                      // 1,008
  // total ~36.9 KB -> 4 blocks/CU

  // ---- stage inputs + zero BF + zero Gk ----
  for (int i = tid; i < DIMD; i += 256) {
    Rn[i] = R_desc[(size_t)n * DIMD + i];
    Rj[i] = R_desc[(size_t)j * DIMD + i];
  }
  if (tid < DIMD) {
    const float* gn = R_d_desc + (size_t)n * (DIMD * 3) + 3 * tid;
    const float* gj = R_d_desc + (size_t)j * (DIMD * 3) + 3 * tid;
    Rdn2[tid] = make_uint2(h16(gn[0]) | (h16(gn[1]) << 16), h16(gn[2]));
    Rdj2[tid] = make_uint2(h16(gj[0]) | (h16(gj[1]) << 16), h16(gj[2]));
  }
  {
    float4 zf = make_float4(0.f, 0.f, 0.f, 0.f);
    float4* mz = (float4*)BF;
    for (int i = tid; i < 4 * 3584 * 2 / 16; i += 256) mz[i] = zf;
    f16x8 z8 = {0, 0, 0, 0, 0, 0, 0, 0};
    for (int i = tid; i < 128; i += 256) ((f16x8*)Gk)[i] = z8;
  }
  __syncthreads();

  // ---- norms ----
  if (tid < 252) {
    int p = tid / 21, seg = tid % 21;
    const int* pp = &perm[p * DIMD + seg * 10];
    const float* rn = &Rn[seg * 10];
    float s = 0.f;
#pragma unroll
    for (int i = 0; i < 10; ++i) {
      float v = rn[i] - Rj[pp[i]];
      s += v * v;
    }
    partial[tid] = s;
  }
  __syncthreads();
  if (tid < NPERM) {
    float s = 0.f;
#pragma unroll
    for (int i = 0; i < 21; ++i) s += partial[tid * 21 + i];
    float nrm = sqrtf(5.0f) * sqrtf(s);
    float mat52 = expf(-nrm / SIGF) * (5.0f / (3.0f * SIGF * SIGF * SIGF * SIGF));
    c1s[tid] = 5.0f * mat52;
    c2s[tid] = (SIGF * SIGF + SIGF * nrm) * mat52;
  }
  __syncthreads();

  // ---- b/G: G -> Gk[row][4+p]; b -> BF slots k=212+p ----
  if (tid < NPERM * NATOM) {
    int p = tid / NATOM, at = tid % NATOM;
    const int* gt = &gtab[(p * NATOM + at) * 20];
    float g0 = 0, g1 = 0, g2 = 0, b0 = 0, b1 = 0, b2 = 0;
#pragma unroll
    for (int i = 0; i < 20; ++i) {
      int v = gt[i];
      int d = v & 511, tw = (v >> 9) & 511, pd = (v >> 18) & 511;
      unsigned sg = ((unsigned)(v & (1 << 27))) << 4;
      float fd = __uint_as_float(__float_as_uint(Rn[d] - Rj[pd]) ^ sg);
      float ftw = __uint_as_float(__float_as_uint(Rn[tw] - Rj[d]) ^ sg);
      uint2 rn = Rdn2[d];
      uint2 rj = Rdj2[d];
      g0 += uh(rn.x) * fd;  g1 += uh(rn.x >> 16) * fd;  g2 += uh(rn.y) * fd;
      b0 += uh(rj.x) * ftw; b1 += uh(rj.x >> 16) * ftw; b2 += uh(rj.y) * ftw;
    }
    float c1 = c1s[p];
    Gk[3 * at + 0][4 + p] = (_Float16)(c1 * g0);
    Gk[3 * at + 1][4 + p] = (_Float16)(c1 * g1);
    Gk[3 * at + 2][4 + p] = (_Float16)(c1 * g2);
    int k = 212 + p;
    BF[fidx(3 * at + 0, k)] = (_Float16)b0;
    BF[fidx(3 * at + 1, k)] = (_Float16)b1;
    BF[fidx(3 * at + 2, k)] = (_Float16)b2;
  }
  // Gk slots 0,1 = A columns d=208 (pair 20,18), d=209 (pair 20,19)
  if (tid < DIMI) {
    int at = tid / 3, u = tid - 3 * at;
    float v208 = (at == 20) ? pick3(Rdn2[208], u)
               : (at == 18) ? -pick3(Rdn2[208], u) : 0.f;
    float v209 = (at == 20) ? pick3(Rdn2[209], u)
               : (at == 19) ? -pick3(Rdn2[209], u) : 0.f;
    Gk[tid][0] = (_Float16)v208;
    Gk[tid][1] = (_Float16)v209;
  }
  // ---- M-build: cell-pair CSR, write-once (no RMW). item w = (a, kpair) ----
  for (int w = tid; w < 2205; w += 256) {
    int a = w / 105, kp = w - a * 105;
    int o0 = aOff[w], o1 = aOff[w + 1];
    if (o0 == o1) continue;   // zero-filled already
    float acc[3][2] = {{0.f, 0.f}, {0.f, 0.f}, {0.f, 0.f}};
    for (int o = o0; o < o1; ++o) {
      int v = aEnts[o];
      int dd = v & 511, p = (v >> 9) & 15, par = (v >> 13) & 1;
      unsigned sgn = ((unsigned)(v & (1 << 14))) << 17;  // bit14 -> bit31
      float c2v = __uint_as_float(__float_as_uint(c2s[p]) ^ sgn);
      uint2 rj = Rdj2[dd];
      acc[0][par] += c2v * uh(rj.x);
      acc[1][par] += c2v * uh(rj.x >> 16);
      acc[2][par] += c2v * uh(rj.y);
    }
    int k2 = kp * 2;
    int Fb = (k2 >> 5) * 512 + (((k2 >> 3) & 3) << 7) + (k2 & 7);
#pragma unroll
    for (int u = 0; u < 3; ++u) {
      int e = 3 * a + u;
      int F = (e >> 4) * 3584 + ((e & 15) << 3) + Fb;
      unsigned val = (h16(acc[u][0]) & 0xFFFFu) | (h16(acc[u][1]) << 16);
      *(unsigned*)((char*)BF + 2 * F) = val;
    }
  }
  __syncthreads();   // BF + Gk ready

  // ---- MFMA: tile = A·M + G^T·b; B-reads contiguous (conflict-free) ----
  f32x4 acc0 = {0.f, 0.f, 0.f, 0.f}, acc1 = acc0, acc2 = acc0, acc3 = acc0;
  const int lane = tid & 63;
  const int nt = tid >> 6;
  const int ci = lane & 15;
  const int kOct = lane >> 4;
  {
    const _Float16* Ag = (const _Float16*)((const char*)ws + A_BYTE_OFF)
                         + (size_t)n * A_PER_N;
    const _Float16* aBase = Ag + ci * 224 + kOct * 8;
    const _Float16* mFrag = BF + nt * 3584 + (kOct << 7) + (ci << 3);
#pragma unroll
    for (int kk = 0; kk < 7; ++kk) {
      f16x8 bf = *(const f16x8*)(mFrag + kk * 512);
      f16x8 a0, a1, a2, a3;
      if (kk == 6 && kOct >= 2) {
        int off = (kOct - 2) * 8;
        a0 = *(const f16x8*)&Gk[ci][off];
        a1 = *(const f16x8*)&Gk[16 + ci][off];
        a2 = *(const f16x8*)&Gk[32 + ci][off];
        a3 = *(const f16x8*)&Gk[48 + ci][off];
      } else {
        a0 = *(const f16x8*)(aBase + kk * 32);
        a1 = *(const f16x8*)(aBase + 16 * 224 + kk * 32);
        a2 = *(const f16x8*)(aBase + 32 * 224 + kk * 32);
        a3 = *(const f16x8*)(aBase + 48 * 224 + kk * 32);
      }
      acc0 = __builtin_amdgcn_mfma_f32_16x16x32_f16(a0, bf, acc0, 0, 0, 0);
      acc1 = __builtin_amdgcn_mfma_f32_16x16x32_f16(a1, bf, acc1, 0, 0, 0);
      acc2 = __builtin_amdgcn_mfma_f32_16x16x32_f16(a2, bf, acc2, 0, 0, 0);
      acc3 = __builtin_amdgcn_mfma_f32_16x16x32_f16(a3, bf, acc3, 0, 0, 0);
    }
  }
  __syncthreads();   // waves done reading BF -> tileH may be written

  {
    // C/D layout (m89): col = lane&15, row = (lane>>4)*4 + reg
    int c = 16 * nt + ci;
    if (c < DIMI) {
      int rb = kOct * 4;
#pragma unroll
      for (int r8 = 0; r8 < 4; ++r8) {
        int r = rb + r8;
        if (r < DIMI) tileH[tswz(r, c)] = (ushort)h16(acc0[r8]);
      }
#pragma unroll
      for (int r8 = 0; r8 < 4; ++r8) {
        int r = 16 + rb + r8;
        tileH[tswz(r, c)] = (ushort)h16(acc1[r8]);
      }
#pragma unroll
      for (int r8 = 0; r8 < 4; ++r8) {
        int r = 32 + rb + r8;
        tileH[tswz(r, c)] = (ushort)h16(acc2[r8]);
      }
#pragma unroll
      for (int r8 = 0; r8 < 4; ++r8) {
        int r = 48 + rb + r8;
        if (r < DIMI) tileH[tswz(r, c)] = (ushort)h16(acc3[r8]);
      }
    }
  }
  __syncthreads();

  // ---- dump ----
  const size_t base = (size_t)n * DIMI * (NCOLS * DIMI) + (size_t)jc * DIMI;
  if (tid < 252) {
    int k = tid >> 2, ec = tid & 3;
    int e0 = ec * 16;
    const uint4* q0 = (const uint4*)&tileH[k * 64 + (((2 * ec) ^ k) & 7) * 8];
    const uint4* q1 = (const uint4*)&tileH[k * 64 + (((2 * ec + 1) ^ k) & 7) * 8];
    uint4 u0 = *q0, u1 = *q1;
    float acc[16];
    acc[0] = uh(u0.x);  acc[1] = uh(u0.x >> 16);
    acc[2] = uh(u0.y);  acc[3] = uh(u0.y >> 16);
    acc[4] = uh(u0.z);  acc[5] = uh(u0.z >> 16);
    acc[6] = uh(u0.w);  acc[7] = uh(u0.w >> 16);
    acc[8] = uh(u1.x);  acc[9] = uh(u1.x >> 16);
    acc[10] = uh(u1.y); acc[11] = uh(u1.y >> 16);
    acc[12] = uh(u1.z); acc[13] = uh(u1.z >> 16);
    acc[14] = uh(u1.w); acc[15] = uh(u1.w >> 16);
    float* op = out + base + (size_t)k * (NCOLS * DIMI) + e0;
    const int lim = DIMI - e0;
#pragma unroll
    for (int i = 0; i < 16; ++i)
      if (i < lim) op[i] = acc[i];
  }
}

// ---------------- fallback CSR kernel (R12) ----------------
__global__ __launch_bounds__(256, 8) void gdml_main_csr(
    const float* __restrict__ R_desc, const float* __restrict__ R_d_desc,
    const int* __restrict__ j_idxs, const int* __restrict__ ws,
    float* __restrict__ out) {
  const int* perm    = ws + WS_PERM;
  const int* gtab    = ws + WS_GTAB;
  const int* entOff  = ws + WS_ENTOFF;
  const int* ents    = ws + WS_ENTS;
  const int* tileMap = ws + WS_TILEMAP;

  const int bid = blockIdx.x;
  const int jc = bid & 7;
  const int n = bid >> 3;
  const int tid = threadIdx.x;
  const int j = j_idxs[jc];

  __shared__ uint2 Rdn2[DIMD];
  __shared__ uint2 Rdj2[DIMD];
  __shared__ __align__(16) float GT[NPERM][64];
  __shared__ __align__(16) float bT[NPERM][64];
  __shared__ float c1s[NPERM], c2s[NPERM];
  __shared__ __align__(16) char uni[DIMI * 64 * 2];
  float* Rn = (float*)uni;
  float* Rj = Rn + DIMD;
  float* partial = Rj + DIMD;
  ushort* tileH = (ushort*)uni;

  for (int i = tid; i < DIMD; i += 256) {
    Rn[i] = R_desc[(size_t)n * DIMD + i];
    Rj[i] = R_desc[(size_t)j * DIMD + i];
  }
  if (tid < DIMD) {
    const float* gn = R_d_desc + (size_t)n * (DIMD * 3) + 3 * tid;
    const float* gj = R_d_desc + (size_t)j * (DIMD * 3) + 3 * tid;
    Rdn2[tid] = make_uint2(h16(gn[0]) | (h16(gn[1]) << 16), h16(gn[2]));
    Rdj2[tid] = make_uint2(h16(gj[0]) | (h16(gj[1]) << 16), h16(gj[2]));
  }
  __syncthreads();

  if (tid < 252) {
    int p = tid / 21, seg = tid % 21;
    const int* pp = &perm[p * DIMD + seg * 10];
    const float* rn = &Rn[seg * 10];
    float s = 0.f;
#pragma unroll
    for (int i = 0; i < 10; ++i) {
      float v = rn[i] - Rj[pp[i]];
      s += v * v;
    }
    partial[tid] = s;
  }
  __syncthreads();
  if (tid < NPERM) {
    float s = 0.f;
#pragma unroll
    for (int i = 0; i < 21; ++i) s += partial[tid * 21 + i];
    float nrm = sqrtf(5.0f) * sqrtf(s);
    float mat52 = expf(-nrm / SIGF) * (5.0f / (3.0f * SIGF * SIGF * SIGF * SIGF));
    c1s[tid] = 5.0f * mat52;
    c2s[tid] = (SIGF * SIGF + SIGF * nrm) * mat52;
  }
  __syncthreads();

  if (tid < NPERM * NATOM) {
    int p = tid / NATOM, at = tid % NATOM;
    const int* gt = &gtab[(p * NATOM + at) * 20];
    float g0 = 0, g1 = 0, g2 = 0, b0 = 0, b1 = 0, b2 = 0;
#pragma unroll
    for (int i = 0; i < 20; ++i) {
      int v = gt[i];
      int d = v & 511, tw = (v >> 9) & 511, pd = (v >> 18) & 511;
      unsigned sg = ((unsigned)(v & (1 << 27))) << 4;
      float fd = __uint_as_float(__float_as_uint(Rn[d] - Rj[pd]) ^ sg);
      float ftw = __uint_as_float(__float_as_uint(Rn[tw] - Rj[d]) ^ sg);
      uint2 rn = Rdn2[d];
      uint2 rj = Rdj2[d];
      g0 += uh(rn.x) * fd;  g1 += uh(rn.x >> 16) * fd;  g2 += uh(rn.y) * fd;
      b0 += uh(rj.x) * ftw; b1 += uh(rj.x >> 16) * ftw; b2 += uh(rj.y) * ftw;
    }
    float c1 = c1s[p];
    GT[p][3 * at + 0] = c1 * g0;
    GT[p][3 * at + 1] = c1 * g1;
    GT[p][3 * at + 2] = c1 * g2;
    bT[p][3 * at + 0] = b0;
    bT[p][3 * at + 1] = b1;
    bT[p][3 * at + 2] = b2;
  }
  __syncthreads();

  for (int s = 0; s < 2; ++s) {
    int rank;
    if (s == 0) { if (tid > 220) break; rank = tid; }
    else        { if (tid >= 220) break; rank = 440 - tid; }
    int q = tileMap[rank];
    int A = q / NATOM, B = q % NATOM;
    float acc[3][3];
#pragma unroll
    for (int c = 0; c < 3; ++c)
#pragma unroll
      for (int e = 0; e < 3; ++e) acc[c][e] = 0.f;

    int o0 = entOff[q], o1 = entOff[q + 1];
    for (int o = o0; o < o1; ++o) {
      int v = ents[o];
      int d8  = v & 0xFF8;
      int dd8 = (v >> 12) & 0xFF8;
      int p4  = (v >> 24) & 0x3C;
      unsigned sgn = ((unsigned)v & 0x40000000u) << 1;
      float c2 = __uint_as_float(
          __float_as_uint(*(const float*)((const char*)c2s + p4)) ^ sgn);
      uint2 rn = *(const uint2*)((const char*)Rdn2 + d8);
      uint2 rj = *(const uint2*)((const char*)Rdj2 + dd8);
      float nx = uh(rn.x), ny = uh(rn.x >> 16), nz = uh(rn.y);
      float w0 = c2 * uh(rj.x), w1 = c2 * uh(rj.x >> 16), w2 = c2 * uh(rj.y);
      acc[0][0] += nx * w0; acc[0][1] += nx * w1; acc[0][2] += nx * w2;
      acc[1][0] += ny * w0; acc[1][1] += ny * w1; acc[1][2] += ny * w2;
      acc[2][0] += nz * w0; acc[2][1] += nz * w1; acc[2][2] += nz * w2;
    }
#pragma unroll
    for (int cg = 0; cg < 3; ++cg) {
      int r = 3 * A + cg;
#pragma unroll
      for (int u = 0; u < 3; ++u)
        tileH[tswz(r, 3 * B + u)] = (ushort)h16(acc[cg][u]);
    }
  }
  __syncthreads();

  const size_t base = (size_t)n * DIMI * (NCOLS * DIMI) + (size_t)jc * DIMI;
  if (tid < 252) {
    int k = tid >> 2, ec = tid & 3;
    int e0 = ec * 16;
    const uint4* q0 = (const uint4*)&tileH[k * 64 + (((2 * ec) ^ k) & 7) * 8];
    const uint4* q1 = (const uint4*)&tileH[k * 64 + (((2 * ec + 1) ^ k) & 7) * 8];
    uint4 u0 = *q0, u1 = *q1;
    float acc[16];
    acc[0] = uh(u0.x);  acc[1] = uh(u0.x >> 16);
    acc[2] = uh(u0.y);  acc[3] = uh(u0.y >> 16);
    acc[4] = uh(u0.z);  acc[5] = uh(u0.z >> 16);
    acc[6] = uh(u0.w);  acc[7] = uh(u0.w >> 16);
    acc[8] = uh(u1.x);  acc[9] = uh(u1.x >> 16);
    acc[10] = uh(u1.y); acc[11] = uh(u1.y >> 16);
    acc[12] = uh(u1.z); acc[13] = uh(u1.z >> 16);
    acc[14] = uh(u1.w); acc[15] = uh(u1.w >> 16);
#pragma unroll
    for (int p = 0; p < NPERM; ++p) {
      float g = GT[p][k];
      const float4* bp = (const float4*)&bT[p][e0];
      float4 b0 = bp[0], b1 = bp[1], b2 = bp[2], b3 = bp[3];
      acc[0] += g * b0.x;  acc[1] += g * b0.y;  acc[2] += g * b0.z;  acc[3] += g * b0.w;
      acc[4] += g * b1.x;  acc[5] += g * b1.y;  acc[6] += g * b1.z;  acc[7] += g * b1.w;
      acc[8] += g * b2.x;  acc[9] += g * b2.y;  acc[10] += g * b2.z; acc[11] += g * b2.w;
      acc[12] += g * b3.x; acc[13] += g * b3.y; acc[14] += g * b3.z; acc[15] += g * b3.w;
    }
    float* op = out + base + (size_t)k * (NCOLS * DIMI) + e0;
    const int lim = DIMI - e0;
#pragma unroll
    for (int i = 0; i < 16; ++i)
      if (i < lim) op[i] = acc[i];
  }
}

extern "C" void kernel_launch(void* const* d_in, const int* in_sizes, int n_in,
                              void* d_out, int out_size, void* d_ws, size_t ws_size,
                              hipStream_t stream) {
  const float* R_desc = (const float*)d_in[0];
  const float* R_d_desc = (const float*)d_in[1];
  const int* tril = (const int*)d_in[2];
  const int* j_idxs = (const int*)d_in[3];
  float* out = (float*)d_out;
  int* ws = (int*)d_ws;

  const int wsBig = (ws_size >= WS_NEEDED) ? 1 : 0;
  hipLaunchKernelGGL(gdml_setup, dim3(1), dim3(512), 0, stream, tril, ws, wsBig);
  if (wsBig) {
    hipLaunchKernelGGL(build_A, dim3(NTRAIN), dim3(256), 0, stream, R_d_desc, ws);
    hipLaunchKernelGGL(gdml_main_mfma, dim3(NTRAIN * NCOLS), dim3(256), 0, stream,
                       R_desc, R_d_desc, j_idxs, ws, out);
  } else {
    hipLaunchKernelGGL(gdml_main_csr, dim3(NTRAIN * NCOLS), dim3(256), 0, stream,
                       R_desc, R_d_desc, j_idxs, ws, out);
  }
}

// Round 17
// 645.550 us; speedup vs baseline: 1.2364x; 1.2364x over previous
//
#include <hip/hip_runtime.h>
#include <hip/hip_fp16.h>
#include <math.h>

#define NTRAIN 2000
#define DIMD 210
#define DIMI 63
#define NPERM 12
#define NCOLS 8
#define NATOM 21
#define SIGF 10.0f

// ws layout (ints):
#define WS_PERM      0        // 2520
#define WS_PAIRROW   5040     // 210
#define WS_PAIRCOL   5250     // 210
#define WS_GTAB      6300     // 5040
#define WS_ENTOFF    11340    // 442
#define WS_ENTS      11782    // 10080
#define WS_TILEMAP   21862    // 441
#define WS_PERMAB    22304    // 2520 (ends 24824)
#define WS_AOFF      24832    // 2206 (cell-pair CSR offsets)
#define WS_AENTS     27040    // 5040 (ends 32080)
#define A_INT_OFF    32768
#define A_BYTE_OFF   (A_INT_OFF * 4)
#define A_PER_N      (64 * 224)
#define A_BYTES      ((size_t)NTRAIN * A_PER_N * 2)
#define WS_NEEDED    ((size_t)A_BYTE_OFF + A_BYTES)

typedef _Float16 f16x8 __attribute__((ext_vector_type(8)));
typedef float f32x4 __attribute__((ext_vector_type(4)));

// ---------------- setup ----------------
__global__ __launch_bounds__(512) void gdml_setup(const int* __restrict__ tril,
                                                  int* __restrict__ ws, int wsBig) {
  __shared__ int sPerm[NPERM * DIMD];
  __shared__ int sInv[NPERM * DIMD];
  __shared__ int sRow[DIMD], sCol[DIMD];
  __shared__ int sPairs[NATOM * 20], sNeg[NATOM * 20];
  __shared__ int sCnt[441];
  __shared__ int sScan[512];
  __shared__ int sOff[442];
  __shared__ int sACnt[2205];

  const int tid = threadIdx.x;

  for (int d = tid; d < DIMD; d += 512) {
    int a = 1;
    while ((a * (a + 1)) / 2 <= d) a++;
    sRow[d] = a;
    sCol[d] = d - (a * (a - 1)) / 2;
  }
  for (int idx = tid; idx < NPERM * DIMD; idx += 512) {
    int p = idx / DIMD, d = idx % DIMD;
    sPerm[idx] = tril[d * NPERM + p] % DIMD;
  }
  __syncthreads();
  for (int idx = tid; idx < NPERM * DIMD; idx += 512) {
    int p = idx / DIMD;
    sInv[p * DIMD + sPerm[idx]] = idx % DIMD;
  }
  if (tid < NATOM) {
    int t = tid, c = 0;
    for (int d = 0; d < DIMD; ++d) {
      if (sRow[d] == t)      { sPairs[t * 20 + c] = d; sNeg[t * 20 + c] = 0; c++; }
      else if (sCol[d] == t) { sPairs[t * 20 + c] = d; sNeg[t * 20 + c] = 1; c++; }
    }
  }
  __syncthreads();

  for (int idx = tid; idx < NPERM * DIMD; idx += 512) ws[WS_PERM + idx] = sPerm[idx];
  for (int d = tid; d < DIMD; d += 512) {
    ws[WS_PAIRROW + d] = sRow[d];
    ws[WS_PAIRCOL + d] = sCol[d];
  }
  // gtab[(p*21+at)*20+i] = d | tw<<9 | pd<<18 | neg<<27
  for (int idx = tid; idx < NPERM * NATOM * 20; idx += 512) {
    int p = idx / (NATOM * 20);
    int r = idx % (NATOM * 20);
    int d = sPairs[r], neg = sNeg[r];
    int tw = sInv[p * DIMD + d];
    int pd = sPerm[p * DIMD + d];
    ws[WS_GTAB + idx] = d | (tw << 9) | (pd << 18) | (neg << 27);
  }
  if (wsBig) {
    for (int idx = tid; idx < NPERM * DIMD; idx += 512) {
      int dd = sPerm[idx];
      ws[WS_PERMAB + idx] = dd | (sRow[dd] << 8) | (sCol[dd] << 13);
    }
  }

  // ---- cell-pair CSR for MFMA M-build: item w=(a, kp); k=invperm[p][dd], kp=k>>1 ----
  for (int w = tid; w < 2205; w += 512) {
    int a = w / 105, kp = w - a * 105, c = 0;
    for (int i = 0; i < 20; ++i) {
      int dd = sPairs[a * 20 + i];
      for (int p = 0; p < NPERM; ++p)
        c += ((sInv[p * DIMD + dd] >> 1) == kp);
    }
    sACnt[w] = c;
  }
  __syncthreads();
  // two-level scan: 441 chunks of 5
  {
    int s = 0;
    if (tid < 441) {
      int lo = tid * 5;
      for (int w = lo; w < lo + 5; ++w) s += sACnt[w];
    }
    sScan[tid] = (tid < 441) ? s : 0;
  }
  __syncthreads();
  for (int s = 1; s < 512; s <<= 1) {
    int v = (tid >= s) ? sScan[tid - s] : 0;
    __syncthreads();
    sScan[tid] += v;
    __syncthreads();
  }
  if (tid < 441) {
    int o = (tid == 0) ? 0 : sScan[tid - 1];
    int lo = tid * 5;
    for (int w = lo; w < lo + 5; ++w) { ws[WS_AOFF + w] = o; o += sACnt[w]; }
  }
  if (tid == 0) ws[WS_AOFF + 2205] = sScan[440];
  __syncthreads();
  // fill: ent = dd | p<<9 | kparity<<13 | negbit<<14  (negbit = negA^1)
  for (int w = tid; w < 2205; w += 512) {
    int a = w / 105, kp = w - a * 105;
    int o = ws[WS_AOFF + w];
    for (int i = 0; i < 20; ++i) {
      int dd = sPairs[a * 20 + i], negA = sNeg[a * 20 + i];
      for (int p = 0; p < NPERM; ++p) {
        int k = sInv[p * DIMD + dd];
        if ((k >> 1) == kp)
          ws[WS_AENTS + (o++)] = dd | (p << 9) | ((k & 1) << 13) | ((negA ^ 1) << 14);
      }
    }
  }

  // ---- fallback-path CSR (R12) ----
  for (int q = tid; q < 441; q += 512) {
    int A = q / NATOM, B = q % NATOM, c = 0;
    for (int i = 0; i < 20; ++i) {
      int d = sPairs[A * 20 + i];
      for (int p = 0; p < NPERM; ++p) {
        int dd = sPerm[p * DIMD + d];
        c += (sRow[dd] == B) + (sCol[dd] == B);
      }
    }
    sCnt[q] = c;
  }
  __syncthreads();
  sScan[tid] = (tid < 441) ? sCnt[tid] : 0;
  __syncthreads();
  for (int s = 1; s < 512; s <<= 1) {
    int v = (tid >= s) ? sScan[tid - s] : 0;
    __syncthreads();
    sScan[tid] += v;
    __syncthreads();
  }
  if (tid == 0) sOff[0] = 0;
  if (tid < 441) sOff[tid + 1] = sScan[tid];
  __syncthreads();
  for (int q = tid; q < 442; q += 512) ws[WS_ENTOFF + q] = sOff[q];
  for (int q = tid; q < 441; q += 512) {
    int c = sCnt[q], r = 0;
    for (int q2 = 0; q2 < 441; ++q2) {
      int c2v = sCnt[q2];
      r += (c2v > c) || (c2v == c && q2 < q);
    }
    ws[WS_TILEMAP + r] = q;
  }
  for (int q = tid; q < 441; q += 512) {
    int A = q / NATOM, B = q % NATOM;
    int o = sOff[q];
    for (int i = 0; i < 20; ++i) {
      int d = sPairs[A * 20 + i];
      int negA = sNeg[A * 20 + i];
      for (int p = 0; p < NPERM; ++p) {
        int dd = sPerm[p * DIMD + d];
        int base = (d << 3) | (dd << 15) | (p << 26);
        if (sRow[dd] == B) ws[WS_ENTS + (o++)] = base | ((negA ^ 1) << 30);
        if (sCol[dd] == B) ws[WS_ENTS + (o++)] = base | (negA << 30);
      }
    }
  }
}

// -------- build A_n = RdnFull^T (fp16 [64][224]) — sparse fill --------
__global__ __launch_bounds__(256) void build_A(const float* __restrict__ R_d_desc,
                                               int* __restrict__ ws) {
  const int bid = blockIdx.x;
  const int n = (bid & 7) * (NTRAIN / 8) + (bid >> 3);
  const int* gtab = ws + WS_GTAB;
  _Float16* A = (_Float16*)((char*)ws + A_BYTE_OFF) + (size_t)n * A_PER_N;
  const float* rd = R_d_desc + (size_t)n * (DIMD * 3);
  const int tid = threadIdx.x;

  f16x8 z = {0, 0, 0, 0, 0, 0, 0, 0};
  for (int u = tid; u < 64 * 28; u += 256) ((f16x8*)A)[u] = z;
  __syncthreads();

  for (int u = tid; u < NATOM * 20; u += 256) {
    int v = gtab[u];
    int d = v & 511;
    float s = (v & (1 << 27)) ? -1.0f : 1.0f;
    int at = u / 20;
    A[(3 * at + 0) * 224 + d] = (_Float16)(s * rd[3 * d + 0]);
    A[(3 * at + 1) * 224 + d] = (_Float16)(s * rd[3 * d + 1]);
    A[(3 * at + 2) * 224 + d] = (_Float16)(s * rd[3 * d + 2]);
  }
}

__device__ inline unsigned h16(float f) {
  return (unsigned)__half_as_ushort(__float2half_rn(f));
}
__device__ inline float uh(unsigned u) {
  return __half2float(__ushort_as_half((unsigned short)(u & 0xFFFFu)));
}
__device__ inline int tswz(int r, int e) {
  return r * 64 + ((((e >> 3) ^ r) & 7) << 3) + (e & 7);
}
__device__ inline float pick3(uint2 v, int u) {
  return (u == 0) ? uh(v.x) : (u == 1) ? uh(v.x >> 16) : uh(v.y);
}
// fragment-major half-index for B operand: e=col (0..63), k (0..223)
__device__ inline int fidx(int e, int k) {
  return (e >> 4) * 3584 + (k >> 5) * 512 + (((k >> 3) & 3) << 7) + ((e & 15) << 3) + (k & 7);
}

// ---------------- MFMA main ----------------
__global__ __launch_bounds__(256, 4) void gdml_main_mfma(
    const float* __restrict__ R_desc, const float* __restrict__ R_d_desc,
    const int* __restrict__ j_idxs, const int* __restrict__ ws,
    float* __restrict__ out) {
  const int* perm  = ws + WS_PERM;
  const int* gtab  = ws + WS_GTAB;
  const int* aOff  = ws + WS_AOFF;
  const int* aEnts = ws + WS_AENTS;

  const int bid = blockIdx.x;
  const int x = bid & 7;
  const int t = bid >> 3;
  const int n = x * (NTRAIN / 8) + (t >> 3);   // XCD-affinity
  const int jc = t & 7;
  const int tid = threadIdx.x;
  const int j = j_idxs[jc];

  // BF: fragment-major B operand [4nt][7kk][4kOct][16ci][8] fp16 (28,672B);
  // tileH (8,064B) aliases it after the MFMA barrier.
  __shared__ __align__(16) char uniBF[4 * 3584 * 2];
  _Float16* BF = (_Float16*)uniBF;
  ushort* tileH = (ushort*)uniBF;
  __shared__ uint2 Rdn2[DIMD];                        // 1,680
  __shared__ uint2 Rdj2[DIMD];                        // 1,680
  __shared__ __align__(16) _Float16 Gk[64][16];       // 2,048
  __shared__ float c1s[NPERM], c2s[NPERM];            // 96
  __shared__ float Rn[DIMD], Rj[DIMD];                // 1,680
  __shared__ float partial[252];                      // 1,008
  // total ~36.9 KB -> 4 blocks/CU

  // ---- stage inputs + zero BF + zero Gk ----
  for (int i = tid; i < DIMD; i += 256) {
    Rn[i] = R_desc[(size_t)n * DIMD + i];
    Rj[i] = R_desc[(size_t)j * DIMD + i];
  }
  if (tid < DIMD) {
    const float* gn = R_d_desc + (size_t)n * (DIMD * 3) + 3 * tid;
    const float* gj = R_d_desc + (size_t)j * (DIMD * 3) + 3 * tid;
    Rdn2[tid] = make_uint2(h16(gn[0]) | (h16(gn[1]) << 16), h16(gn[2]));
    Rdj2[tid] = make_uint2(h16(gj[0]) | (h16(gj[1]) << 16), h16(gj[2]));
  }
  {
    float4 zf = make_float4(0.f, 0.f, 0.f, 0.f);
    float4* mz = (float4*)BF;
    for (int i = tid; i < 4 * 3584 * 2 / 16; i += 256) mz[i] = zf;
    f16x8 z8 = {0, 0, 0, 0, 0, 0, 0, 0};
    for (int i = tid; i < 128; i += 256) ((f16x8*)Gk)[i] = z8;
  }
  __syncthreads();

  // ---- norms ----
  if (tid < 252) {
    int p = tid / 21, seg = tid % 21;
    const int* pp = &perm[p * DIMD + seg * 10];
    const float* rn = &Rn[seg * 10];
    float s = 0.f;
#pragma unroll
    for (int i = 0; i < 10; ++i) {
      float v = rn[i] - Rj[pp[i]];
      s += v * v;
    }
    partial[tid] = s;
  }
  __syncthreads();
  if (tid < NPERM) {
    float s = 0.f;
#pragma unroll
    for (int i = 0; i < 21; ++i) s += partial[tid * 21 + i];
    float nrm = sqrtf(5.0f) * sqrtf(s);
    float mat52 = expf(-nrm / SIGF) * (5.0f / (3.0f * SIGF * SIGF * SIGF * SIGF));
    c1s[tid] = 5.0f * mat52;
    c2s[tid] = (SIGF * SIGF + SIGF * nrm) * mat52;
  }
  __syncthreads();

  // ---- b/G: G -> Gk[row][4+p]; b -> BF slots k=212+p ----
  if (tid < NPERM * NATOM) {
    int p = tid / NATOM, at = tid % NATOM;
    const int* gt = &gtab[(p * NATOM + at) * 20];
    float g0 = 0, g1 = 0, g2 = 0, b0 = 0, b1 = 0, b2 = 0;
#pragma unroll
    for (int i = 0; i < 20; ++i) {
      int v = gt[i];
      int d = v & 511, tw = (v >> 9) & 511, pd = (v >> 18) & 511;
      unsigned sg = ((unsigned)(v & (1 << 27))) << 4;
      float fd = __uint_as_float(__float_as_uint(Rn[d] - Rj[pd]) ^ sg);
      float ftw = __uint_as_float(__float_as_uint(Rn[tw] - Rj[d]) ^ sg);
      uint2 rn = Rdn2[d];
      uint2 rj = Rdj2[d];
      g0 += uh(rn.x) * fd;  g1 += uh(rn.x >> 16) * fd;  g2 += uh(rn.y) * fd;
      b0 += uh(rj.x) * ftw; b1 += uh(rj.x >> 16) * ftw; b2 += uh(rj.y) * ftw;
    }
    float c1 = c1s[p];
    Gk[3 * at + 0][4 + p] = (_Float16)(c1 * g0);
    Gk[3 * at + 1][4 + p] = (_Float16)(c1 * g1);
    Gk[3 * at + 2][4 + p] = (_Float16)(c1 * g2);
    int k = 212 + p;
    BF[fidx(3 * at + 0, k)] = (_Float16)b0;
    BF[fidx(3 * at + 1, k)] = (_Float16)b1;
    BF[fidx(3 * at + 2, k)] = (_Float16)b2;
  }
  // Gk slots 0,1 = A columns d=208 (pair 20,18), d=209 (pair 20,19)
  if (tid < DIMI) {
    int at = tid / 3, u = tid - 3 * at;
    float v208 = (at == 20) ? pick3(Rdn2[208], u)
               : (at == 18) ? -pick3(Rdn2[208], u) : 0.f;
    float v209 = (at == 20) ? pick3(Rdn2[209], u)
               : (at == 19) ? -pick3(Rdn2[209], u) : 0.f;
    Gk[tid][0] = (_Float16)v208;
    Gk[tid][1] = (_Float16)v209;
  }
  // ---- M-build: cell-pair CSR, write-once. NAMED scalar accs (rule #20 fix) ----
  for (int w = tid; w < 2205; w += 256) {
    int a = w / 105, kp = w - a * 105;
    int o0 = aOff[w], o1 = aOff[w + 1];
    if (o0 == o1) continue;   // zero-filled already
    float a00 = 0.f, a10 = 0.f, a20 = 0.f;   // parity 0
    float a01 = 0.f, a11 = 0.f, a21 = 0.f;   // parity 1
    for (int o = o0; o < o1; ++o) {
      int v = aEnts[o];
      int dd = v & 511, p = (v >> 9) & 15;
      unsigned sgn = ((unsigned)(v & (1 << 14))) << 17;  // bit14 -> bit31
      float c2v = __uint_as_float(__float_as_uint(c2s[p]) ^ sgn);
      uint2 rj = Rdj2[dd];
      float w0 = c2v * uh(rj.x), w1 = c2v * uh(rj.x >> 16), w2 = c2v * uh(rj.y);
      float mp = (float)((v >> 13) & 1);   // parity select via multiply-mask
      float mn = 1.0f - mp;
      a00 += mn * w0; a10 += mn * w1; a20 += mn * w2;
      a01 += mp * w0; a11 += mp * w1; a21 += mp * w2;
    }
    int k2 = kp * 2;
    int Fb = (k2 >> 5) * 512 + (((k2 >> 3) & 3) << 7) + (k2 & 7);
    int Fe = (3 * a >> 4) * 3584;   // note: e = 3a+u may cross 16-boundary; compute per u
#pragma unroll
    for (int u = 0; u < 3; ++u) {
      int e = 3 * a + u;
      int F = (e >> 4) * 3584 + ((e & 15) << 3) + Fb;
      float lo = (u == 0) ? a00 : (u == 1) ? a10 : a20;
      float hi = (u == 0) ? a01 : (u == 1) ? a11 : a21;
      unsigned val = (h16(lo) & 0xFFFFu) | (h16(hi) << 16);
      *(unsigned*)((char*)BF + 2 * F) = val;
    }
    (void)Fe;
  }
  __syncthreads();   // BF + Gk ready

  // ---- MFMA: tile = A·M + G^T·b; B-reads contiguous (conflict-free) ----
  f32x4 acc0 = {0.f, 0.f, 0.f, 0.f}, acc1 = acc0, acc2 = acc0, acc3 = acc0;
  const int lane = tid & 63;
  const int nt = tid >> 6;
  const int ci = lane & 15;
  const int kOct = lane >> 4;
  {
    const _Float16* Ag = (const _Float16*)((const char*)ws + A_BYTE_OFF)
                         + (size_t)n * A_PER_N;
    const _Float16* aBase = Ag + ci * 224 + kOct * 8;
    const _Float16* mFrag = BF + nt * 3584 + (kOct << 7) + (ci << 3);
#pragma unroll
    for (int kk = 0; kk < 7; ++kk) {
      f16x8 bf = *(const f16x8*)(mFrag + kk * 512);
      f16x8 a0, a1, a2, a3;
      if (kk == 6 && kOct >= 2) {
        int off = (kOct - 2) * 8;
        a0 = *(const f16x8*)&Gk[ci][off];
        a1 = *(const f16x8*)&Gk[16 + ci][off];
        a2 = *(const f16x8*)&Gk[32 + ci][off];
        a3 = *(const f16x8*)&Gk[48 + ci][off];
      } else {
        a0 = *(const f16x8*)(aBase + kk * 32);
        a1 = *(const f16x8*)(aBase + 16 * 224 + kk * 32);
        a2 = *(const f16x8*)(aBase + 32 * 224 + kk * 32);
        a3 = *(const f16x8*)(aBase + 48 * 224 + kk * 32);
      }
      acc0 = __builtin_amdgcn_mfma_f32_16x16x32_f16(a0, bf, acc0, 0, 0, 0);
      acc1 = __builtin_amdgcn_mfma_f32_16x16x32_f16(a1, bf, acc1, 0, 0, 0);
      acc2 = __builtin_amdgcn_mfma_f32_16x16x32_f16(a2, bf, acc2, 0, 0, 0);
      acc3 = __builtin_amdgcn_mfma_f32_16x16x32_f16(a3, bf, acc3, 0, 0, 0);
    }
  }
  __syncthreads();   // waves done reading BF -> tileH may be written

  {
    // C/D layout (m89): col = lane&15, row = (lane>>4)*4 + reg
    int c = 16 * nt + ci;
    if (c < DIMI) {
      int rb = kOct * 4;
#pragma unroll
      for (int r8 = 0; r8 < 4; ++r8) {
        int r = rb + r8;
        if (r < DIMI) tileH[tswz(r, c)] = (ushort)h16(acc0[r8]);
      }
#pragma unroll
      for (int r8 = 0; r8 < 4; ++r8) {
        int r = 16 + rb + r8;
        tileH[tswz(r, c)] = (ushort)h16(acc1[r8]);
      }
#pragma unroll
      for (int r8 = 0; r8 < 4; ++r8) {
        int r = 32 + rb + r8;
        tileH[tswz(r, c)] = (ushort)h16(acc2[r8]);
      }
#pragma unroll
      for (int r8 = 0; r8 < 4; ++r8) {
        int r = 48 + rb + r8;
        if (r < DIMI) tileH[tswz(r, c)] = (ushort)h16(acc3[r8]);
      }
    }
  }
  __syncthreads();

  // ---- dump ----
  const size_t base = (size_t)n * DIMI * (NCOLS * DIMI) + (size_t)jc * DIMI;
  if (tid < 252) {
    int k = tid >> 2, ec = tid & 3;
    int e0 = ec * 16;
    const uint4* q0 = (const uint4*)&tileH[k * 64 + (((2 * ec) ^ k) & 7) * 8];
    const uint4* q1 = (const uint4*)&tileH[k * 64 + (((2 * ec + 1) ^ k) & 7) * 8];
    uint4 u0 = *q0, u1 = *q1;
    float acc[16];
    acc[0] = uh(u0.x);  acc[1] = uh(u0.x >> 16);
    acc[2] = uh(u0.y);  acc[3] = uh(u0.y >> 16);
    acc[4] = uh(u0.z);  acc[5] = uh(u0.z >> 16);
    acc[6] = uh(u0.w);  acc[7] = uh(u0.w >> 16);
    acc[8] = uh(u1.x);  acc[9] = uh(u1.x >> 16);
    acc[10] = uh(u1.y); acc[11] = uh(u1.y >> 16);
    acc[12] = uh(u1.z); acc[13] = uh(u1.z >> 16);
    acc[14] = uh(u1.w); acc[15] = uh(u1.w >> 16);
    float* op = out + base + (size_t)k * (NCOLS * DIMI) + e0;
    const int lim = DIMI - e0;
#pragma unroll
    for (int i = 0; i < 16; ++i)
      if (i < lim) op[i] = acc[i];
  }
}

// ---------------- fallback CSR kernel (R12) ----------------
__global__ __launch_bounds__(256, 8) void gdml_main_csr(
    const float* __restrict__ R_desc, const float* __restrict__ R_d_desc,
    const int* __restrict__ j_idxs, const int* __restrict__ ws,
    float* __restrict__ out) {
  const int* perm    = ws + WS_PERM;
  const int* gtab    = ws + WS_GTAB;
  const int* entOff  = ws + WS_ENTOFF;
  const int* ents    = ws + WS_ENTS;
  const int* tileMap = ws + WS_TILEMAP;

  const int bid = blockIdx.x;
  const int jc = bid & 7;
  const int n = bid >> 3;
  const int tid = threadIdx.x;
  const int j = j_idxs[jc];

  __shared__ uint2 Rdn2[DIMD];
  __shared__ uint2 Rdj2[DIMD];
  __shared__ __align__(16) float GT[NPERM][64];
  __shared__ __align__(16) float bT[NPERM][64];
  __shared__ float c1s[NPERM], c2s[NPERM];
  __shared__ __align__(16) char uni[DIMI * 64 * 2];
  float* Rn = (float*)uni;
  float* Rj = Rn + DIMD;
  float* partial = Rj + DIMD;
  ushort* tileH = (ushort*)uni;

  for (int i = tid; i < DIMD; i += 256) {
    Rn[i] = R_desc[(size_t)n * DIMD + i];
    Rj[i] = R_desc[(size_t)j * DIMD + i];
  }
  if (tid < DIMD) {
    const float* gn = R_d_desc + (size_t)n * (DIMD * 3) + 3 * tid;
    const float* gj = R_d_desc + (size_t)j * (DIMD * 3) + 3 * tid;
    Rdn2[tid] = make_uint2(h16(gn[0]) | (h16(gn[1]) << 16), h16(gn[2]));
    Rdj2[tid] = make_uint2(h16(gj[0]) | (h16(gj[1]) << 16), h16(gj[2]));
  }
  __syncthreads();

  if (tid < 252) {
    int p = tid / 21, seg = tid % 21;
    const int* pp = &perm[p * DIMD + seg * 10];
    const float* rn = &Rn[seg * 10];
    float s = 0.f;
#pragma unroll
    for (int i = 0; i < 10; ++i) {
      float v = rn[i] - Rj[pp[i]];
      s += v * v;
    }
    partial[tid] = s;
  }
  __syncthreads();
  if (tid < NPERM) {
    float s = 0.f;
#pragma unroll
    for (int i = 0; i < 21; ++i) s += partial[tid * 21 + i];
    float nrm = sqrtf(5.0f) * sqrtf(s);
    float mat52 = expf(-nrm / SIGF) * (5.0f / (3.0f * SIGF * SIGF * SIGF * SIGF));
    c1s[tid] = 5.0f * mat52;
    c2s[tid] = (SIGF * SIGF + SIGF * nrm) * mat52;
  }
  __syncthreads();

  if (tid < NPERM * NATOM) {
    int p = tid / NATOM, at = tid % NATOM;
    const int* gt = &gtab[(p * NATOM + at) * 20];
    float g0 = 0, g1 = 0, g2 = 0, b0 = 0, b1 = 0, b2 = 0;
#pragma unroll
    for (int i = 0; i < 20; ++i) {
      int v = gt[i];
      int d = v & 511, tw = (v >> 9) & 511, pd = (v >> 18) & 511;
      unsigned sg = ((unsigned)(v & (1 << 27))) << 4;
      float fd = __uint_as_float(__float_as_uint(Rn[d] - Rj[pd]) ^ sg);
      float ftw = __uint_as_float(__float_as_uint(Rn[tw] - Rj[d]) ^ sg);
      uint2 rn = Rdn2[d];
      uint2 rj = Rdj2[d];
      g0 += uh(rn.x) * fd;  g1 += uh(rn.x >> 16) * fd;  g2 += uh(rn.y) * fd;
      b0 += uh(rj.x) * ftw; b1 += uh(rj.x >> 16) * ftw; b2 += uh(rj.y) * ftw;
    }
    float c1 = c1s[p];
    GT[p][3 * at + 0] = c1 * g0;
    GT[p][3 * at + 1] = c1 * g1;
    GT[p][3 * at + 2] = c1 * g2;
    bT[p][3 * at + 0] = b0;
    bT[p][3 * at + 1] = b1;
    bT[p][3 * at + 2] = b2;
  }
  __syncthreads();

  for (int s = 0; s < 2; ++s) {
    int rank;
    if (s == 0) { if (tid > 220) break; rank = tid; }
    else        { if (tid >= 220) break; rank = 440 - tid; }
    int q = tileMap[rank];
    int A = q / NATOM, B = q % NATOM;
    float acc[3][3];
#pragma unroll
    for (int c = 0; c < 3; ++c)
#pragma unroll
      for (int e = 0; e < 3; ++e) acc[c][e] = 0.f;

    int o0 = entOff[q], o1 = entOff[q + 1];
    for (int o = o0; o < o1; ++o) {
      int v = ents[o];
      int d8  = v & 0xFF8;
      int dd8 = (v >> 12) & 0xFF8;
      int p4  = (v >> 24) & 0x3C;
      unsigned sgn = ((unsigned)v & 0x40000000u) << 1;
      float c2 = __uint_as_float(
          __float_as_uint(*(const float*)((const char*)c2s + p4)) ^ sgn);
      uint2 rn = *(const uint2*)((const char*)Rdn2 + d8);
      uint2 rj = *(const uint2*)((const char*)Rdj2 + dd8);
      float nx = uh(rn.x), ny = uh(rn.x >> 16), nz = uh(rn.y);
      float w0 = c2 * uh(rj.x), w1 = c2 * uh(rj.x >> 16), w2 = c2 * uh(rj.y);
      acc[0][0] += nx * w0; acc[0][1] += nx * w1; acc[0][2] += nx * w2;
      acc[1][0] += ny * w0; acc[1][1] += ny * w1; acc[1][2] += ny * w2;
      acc[2][0] += nz * w0; acc[2][1] += nz * w1; acc[2][2] += nz * w2;
    }
#pragma unroll
    for (int cg = 0; cg < 3; ++cg) {
      int r = 3 * A + cg;
#pragma unroll
      for (int u = 0; u < 3; ++u)
        tileH[tswz(r, 3 * B + u)] = (ushort)h16(acc[cg][u]);
    }
  }
  __syncthreads();

  const size_t base = (size_t)n * DIMI * (NCOLS * DIMI) + (size_t)jc * DIMI;
  if (tid < 252) {
    int k = tid >> 2, ec = tid & 3;
    int e0 = ec * 16;
    const uint4* q0 = (const uint4*)&tileH[k * 64 + (((2 * ec) ^ k) & 7) * 8];
    const uint4* q1 = (const uint4*)&tileH[k * 64 + (((2 * ec + 1) ^ k) & 7) * 8];
    uint4 u0 = *q0, u1 = *q1;
    float acc[16];
    acc[0] = uh(u0.x);  acc[1] = uh(u0.x >> 16);
    acc[2] = uh(u0.y);  acc[3] = uh(u0.y >> 16);
    acc[4] = uh(u0.z);  acc[5] = uh(u0.z >> 16);
    acc[6] = uh(u0.w);  acc[7] = uh(u0.w >> 16);
    acc[8] = uh(u1.x);  acc[9] = uh(u1.x >> 16);
    acc[10] = uh(u1.y); acc[11] = uh(u1.y >> 16);
    acc[12] = uh(u1.z); acc[13] = uh(u1.z >> 16);
    acc[14] = uh(u1.w); acc[15] = uh(u1.w >> 16);
#pragma unroll
    for (int p = 0; p < NPERM; ++p) {
      float g = GT[p][k];
      const float4* bp = (const float4*)&bT[p][e0];
      float4 b0 = bp[0], b1 = bp[1], b2 = bp[2], b3 = bp[3];
      acc[0] += g * b0.x;  acc[1] += g * b0.y;  acc[2] += g * b0.z;  acc[3] += g * b0.w;
      acc[4] += g * b1.x;  acc[5] += g * b1.y;  acc[6] += g * b1.z;  acc[7] += g * b1.w;
      acc[8] += g * b2.x;  acc[9] += g * b2.y;  acc[10] += g * b2.z; acc[11] += g * b2.w;
      acc[12] += g * b3.x; acc[13] += g * b3.y; acc[14] += g * b3.z; acc[15] += g * b3.w;
    }
    float* op = out + base + (size_t)k * (NCOLS * DIMI) + e0;
    const int lim = DIMI - e0;
#pragma unroll
    for (int i = 0; i < 16; ++i)
      if (i < lim) op[i] = acc[i];
  }
}

extern "C" void kernel_launch(void* const* d_in, const int* in_sizes, int n_in,
                              void* d_out, int out_size, void* d_ws, size_t ws_size,
                              hipStream_t stream) {
  const float* R_desc = (const float*)d_in[0];
  const float* R_d_desc = (const float*)d_in[1];
  const int* tril = (const int*)d_in[2];
  const int* j_idxs = (const int*)d_in[3];
  float* out = (float*)d_out;
  int* ws = (int*)d_ws;

  const int wsBig = (ws_size >= WS_NEEDED) ? 1 : 0;
  hipLaunchKernelGGL(gdml_setup, dim3(1), dim3(512), 0, stream, tril, ws, wsBig);
  if (wsBig) {
    hipLaunchKernelGGL(build_A, dim3(NTRAIN), dim3(256), 0, stream, R_d_desc, ws);
    hipLaunchKernelGGL(gdml_main_mfma, dim3(NTRAIN * NCOLS), dim3(256), 0, stream,
                       R_desc, R_d_desc, j_idxs, ws, out);
  } else {
    hipLaunchKernelGGL(gdml_main_csr, dim3(NTRAIN * NCOLS), dim3(256), 0, stream,
                       R_desc, R_d_desc, j_idxs, ws, out);
  }
}

// Round 18
// 341.729 us; speedup vs baseline: 2.3356x; 1.8891x over previous
//
#include <hip/hip_runtime.h>
#include <hip/hip_fp16.h>
#include <math.h>

#define NTRAIN 2000
#define DIMD 210
#define DIMI 63
#define NPERM 12
#define NCOLS 8
#define NATOM 21
#define SIGF 10.0f

// ws layout (ints):
#define WS_PERM      0        // 2520
#define WS_PAIRROW   5040     // 210
#define WS_PAIRCOL   5250     // 210
#define WS_GTAB      6300     // 5040
#define WS_ENTOFF    11340    // 442
#define WS_ENTS      11782    // 10080
#define WS_TILEMAP   21862    // 441
#define WS_PERMAB    22304    // 2520 (ends 24824)
#define A_INT_OFF    25088
#define A_BYTE_OFF   (A_INT_OFF * 4)
#define A_PER_N      (64 * 224)
#define A_BYTES      ((size_t)NTRAIN * A_PER_N * 2)
#define WS_NEEDED    ((size_t)A_BYTE_OFF + A_BYTES)

typedef _Float16 f16x8 __attribute__((ext_vector_type(8)));
typedef float f32x4 __attribute__((ext_vector_type(4)));

// ---------------- setup (R15 verbatim) ----------------
__global__ __launch_bounds__(512) void gdml_setup(const int* __restrict__ tril,
                                                  int* __restrict__ ws, int wsBig) {
  __shared__ int sPerm[NPERM * DIMD];
  __shared__ int sInv[NPERM * DIMD];
  __shared__ int sRow[DIMD], sCol[DIMD];
  __shared__ int sPairs[NATOM * 20], sNeg[NATOM * 20];
  __shared__ int sCnt[441];
  __shared__ int sScan[512];
  __shared__ int sOff[442];

  const int tid = threadIdx.x;

  for (int d = tid; d < DIMD; d += 512) {
    int a = 1;
    while ((a * (a + 1)) / 2 <= d) a++;
    sRow[d] = a;
    sCol[d] = d - (a * (a - 1)) / 2;
  }
  for (int idx = tid; idx < NPERM * DIMD; idx += 512) {
    int p = idx / DIMD, d = idx % DIMD;
    sPerm[idx] = tril[d * NPERM + p] % DIMD;
  }
  __syncthreads();
  for (int idx = tid; idx < NPERM * DIMD; idx += 512) {
    int p = idx / DIMD;
    sInv[p * DIMD + sPerm[idx]] = idx % DIMD;
  }
  if (tid < NATOM) {
    int t = tid, c = 0;
    for (int d = 0; d < DIMD; ++d) {
      if (sRow[d] == t)      { sPairs[t * 20 + c] = d; sNeg[t * 20 + c] = 0; c++; }
      else if (sCol[d] == t) { sPairs[t * 20 + c] = d; sNeg[t * 20 + c] = 1; c++; }
    }
  }
  __syncthreads();

  for (int idx = tid; idx < NPERM * DIMD; idx += 512) ws[WS_PERM + idx] = sPerm[idx];
  for (int d = tid; d < DIMD; d += 512) {
    ws[WS_PAIRROW + d] = sRow[d];
    ws[WS_PAIRCOL + d] = sCol[d];
  }
  for (int idx = tid; idx < NPERM * NATOM * 20; idx += 512) {
    int p = idx / (NATOM * 20);
    int r = idx % (NATOM * 20);
    int d = sPairs[r], neg = sNeg[r];
    int tw = sInv[p * DIMD + d];
    int pd = sPerm[p * DIMD + d];
    ws[WS_GTAB + idx] = d | (tw << 9) | (pd << 18) | (neg << 27);
  }
  if (wsBig) {
    for (int idx = tid; idx < NPERM * DIMD; idx += 512) {
      int dd = sPerm[idx];
      ws[WS_PERMAB + idx] = dd | (sRow[dd] << 8) | (sCol[dd] << 13);
    }
  }

  for (int q = tid; q < 441; q += 512) {
    int A = q / NATOM, B = q % NATOM, c = 0;
    for (int i = 0; i < 20; ++i) {
      int d = sPairs[A * 20 + i];
      for (int p = 0; p < NPERM; ++p) {
        int dd = sPerm[p * DIMD + d];
        c += (sRow[dd] == B) + (sCol[dd] == B);
      }
    }
    sCnt[q] = c;
  }
  __syncthreads();

  sScan[tid] = (tid < 441) ? sCnt[tid] : 0;
  __syncthreads();
  for (int s = 1; s < 512; s <<= 1) {
    int v = (tid >= s) ? sScan[tid - s] : 0;
    __syncthreads();
    sScan[tid] += v;
    __syncthreads();
  }
  if (tid == 0) sOff[0] = 0;
  if (tid < 441) sOff[tid + 1] = sScan[tid];
  __syncthreads();
  for (int q = tid; q < 442; q += 512) ws[WS_ENTOFF + q] = sOff[q];

  for (int q = tid; q < 441; q += 512) {
    int c = sCnt[q], r = 0;
    for (int q2 = 0; q2 < 441; ++q2) {
      int c2v = sCnt[q2];
      r += (c2v > c) || (c2v == c && q2 < q);
    }
    ws[WS_TILEMAP + r] = q;
  }

  for (int q = tid; q < 441; q += 512) {
    int A = q / NATOM, B = q % NATOM;
    int o = sOff[q];
    for (int i = 0; i < 20; ++i) {
      int d = sPairs[A * 20 + i];
      int negA = sNeg[A * 20 + i];
      for (int p = 0; p < NPERM; ++p) {
        int dd = sPerm[p * DIMD + d];
        int base = (d << 3) | (dd << 15) | (p << 26);
        if (sRow[dd] == B) ws[WS_ENTS + (o++)] = base | ((negA ^ 1) << 30);
        if (sCol[dd] == B) ws[WS_ENTS + (o++)] = base | (negA << 30);
      }
    }
  }
}

// -------- build A_n = RdnFull^T (fp16 [64][224]) — sparse fill --------
__global__ __launch_bounds__(256) void build_A(const float* __restrict__ R_d_desc,
                                               int* __restrict__ ws) {
  const int bid = blockIdx.x;
  const int n = (bid & 7) * (NTRAIN / 8) + (bid >> 3);  // XCD-affine
  const int* gtab = ws + WS_GTAB;
  _Float16* A = (_Float16*)((char*)ws + A_BYTE_OFF) + (size_t)n * A_PER_N;
  const float* rd = R_d_desc + (size_t)n * (DIMD * 3);
  const int tid = threadIdx.x;

  f16x8 z = {0, 0, 0, 0, 0, 0, 0, 0};
  for (int u = tid; u < 64 * 28; u += 256) ((f16x8*)A)[u] = z;
  __syncthreads();

  for (int u = tid; u < NATOM * 20; u += 256) {
    int v = gtab[u];            // p=0 rows
    int d = v & 511;
    float s = (v & (1 << 27)) ? -1.0f : 1.0f;
    int at = u / 20;
    A[(3 * at + 0) * 224 + d] = (_Float16)(s * rd[3 * d + 0]);
    A[(3 * at + 1) * 224 + d] = (_Float16)(s * rd[3 * d + 1]);
    A[(3 * at + 2) * 224 + d] = (_Float16)(s * rd[3 * d + 2]);
  }
}

__device__ inline unsigned h16(float f) {
  return (unsigned)__half_as_ushort(__float2half_rn(f));
}
__device__ inline float uh(unsigned u) {
  return __half2float(__ushort_as_half((unsigned short)(u & 0xFFFFu)));
}
__device__ inline int tswz(int r, int e) {
  return r * 64 + ((((e >> 3) ^ r) & 7) << 3) + (e & 7);
}
__device__ inline float pick3(uint2 v, int u) {
  return (u == 0) ? uh(v.x) : (u == 1) ? uh(v.x >> 16) : uh(v.y);
}

#define MT_STRIDE 232

// ---------------- MFMA main: R15 structure, direct global store (no tile/dump) ----
__global__ __launch_bounds__(256, 4) void gdml_main_mfma(
    const float* __restrict__ R_desc, const float* __restrict__ R_d_desc,
    const int* __restrict__ j_idxs, const int* __restrict__ ws,
    float* __restrict__ out) {
  const int* perm   = ws + WS_PERM;
  const int* gtab   = ws + WS_GTAB;
  const int* permAB = ws + WS_PERMAB;

  const int bid = blockIdx.x;
  const int x = bid & 7;
  const int t = bid >> 3;
  const int n = x * (NTRAIN / 8) + (t >> 3);   // XCD-affinity
  const int jc = t & 7;
  const int tid = threadIdx.x;
  const int j = j_idxs[jc];

  __shared__ __align__(16) _Float16 MT[64 * MT_STRIDE]; // 29,696
  __shared__ uint2 Rdn2[DIMD];                        // 1,680
  __shared__ uint2 Rdj2[DIMD];                        // 1,680
  __shared__ __align__(16) _Float16 Gk[64][16];       // 2,048
  __shared__ float c1s[NPERM], c2s[NPERM];            // 96
  __shared__ float Rn[DIMD], Rj[DIMD];                // 1,680
  __shared__ float partial[252];                      // 1,008
  // total ~37.9 KB -> 4 blocks/CU

  // ---- stage inputs + zero MT + zero Gk ----
  for (int i = tid; i < DIMD; i += 256) {
    Rn[i] = R_desc[(size_t)n * DIMD + i];
    Rj[i] = R_desc[(size_t)j * DIMD + i];
  }
  if (tid < DIMD) {
    const float* gn = R_d_desc + (size_t)n * (DIMD * 3) + 3 * tid;
    const float* gj = R_d_desc + (size_t)j * (DIMD * 3) + 3 * tid;
    Rdn2[tid] = make_uint2(h16(gn[0]) | (h16(gn[1]) << 16), h16(gn[2]));
    Rdj2[tid] = make_uint2(h16(gj[0]) | (h16(gj[1]) << 16), h16(gj[2]));
  }
  {
    float4 zf = make_float4(0.f, 0.f, 0.f, 0.f);
    float4* mz = (float4*)MT;
    for (int i = tid; i < 64 * MT_STRIDE * 2 / 16; i += 256) mz[i] = zf;
    f16x8 z8 = {0, 0, 0, 0, 0, 0, 0, 0};
    for (int i = tid; i < 128; i += 256) ((f16x8*)Gk)[i] = z8;
  }
  __syncthreads();

  // ---- norms ----
  if (tid < 252) {
    int p = tid / 21, seg = tid % 21;
    const int* pp = &perm[p * DIMD + seg * 10];
    const float* rn = &Rn[seg * 10];
    float s = 0.f;
#pragma unroll
    for (int i = 0; i < 10; ++i) {
      float v = rn[i] - Rj[pp[i]];
      s += v * v;
    }
    partial[tid] = s;
  }
  __syncthreads();
  if (tid < NPERM) {
    float s = 0.f;
#pragma unroll
    for (int i = 0; i < 21; ++i) s += partial[tid * 21 + i];
    float nrm = sqrtf(5.0f) * sqrtf(s);
    float mat52 = expf(-nrm / SIGF) * (5.0f / (3.0f * SIGF * SIGF * SIGF * SIGF));
    c1s[tid] = 5.0f * mat52;
    c2s[tid] = (SIGF * SIGF + SIGF * nrm) * mat52;
  }
  __syncthreads();

  // ---- b/G: G -> Gk[row][4+p] fp16; b -> MT[e][212+p] fp16 ----
  if (tid < NPERM * NATOM) {
    int p = tid / NATOM, at = tid % NATOM;
    const int* gt = &gtab[(p * NATOM + at) * 20];
    float g0 = 0, g1 = 0, g2 = 0, b0 = 0, b1 = 0, b2 = 0;
#pragma unroll
    for (int i = 0; i < 20; ++i) {
      int v = gt[i];
      int d = v & 511, tw = (v >> 9) & 511, pd = (v >> 18) & 511;
      unsigned sg = ((unsigned)(v & (1 << 27))) << 4;
      float fd = __uint_as_float(__float_as_uint(Rn[d] - Rj[pd]) ^ sg);
      float ftw = __uint_as_float(__float_as_uint(Rn[tw] - Rj[d]) ^ sg);
      uint2 rn = Rdn2[d];
      uint2 rj = Rdj2[d];
      g0 += uh(rn.x) * fd;  g1 += uh(rn.x >> 16) * fd;  g2 += uh(rn.y) * fd;
      b0 += uh(rj.x) * ftw; b1 += uh(rj.x >> 16) * ftw; b2 += uh(rj.y) * ftw;
    }
    float c1 = c1s[p];
    Gk[3 * at + 0][4 + p] = (_Float16)(c1 * g0);
    Gk[3 * at + 1][4 + p] = (_Float16)(c1 * g1);
    Gk[3 * at + 2][4 + p] = (_Float16)(c1 * g2);
    MT[(3 * at + 0) * MT_STRIDE + 212 + p] = (_Float16)b0;
    MT[(3 * at + 1) * MT_STRIDE + 212 + p] = (_Float16)b1;
    MT[(3 * at + 2) * MT_STRIDE + 212 + p] = (_Float16)b2;
  }

  // ---- M-build (tid<210) + Gk slots 0,1 (tid 210..255) ----
  if (tid < DIMD) {
    int d = tid;
    _Float16* m = MT + d;
#pragma unroll
    for (int p = 0; p < NPERM; ++p) {
      int v = permAB[p * DIMD + d];
      int dd = v & 255, a = (v >> 8) & 31, b = (v >> 13) & 31;
      float c2 = c2s[p];
      uint2 rj = Rdj2[dd];
      float v0 = c2 * uh(rj.x), v1 = c2 * uh(rj.x >> 16), v2 = c2 * uh(rj.y);
      int ca = (3 * a) * MT_STRIDE, cb = (3 * b) * MT_STRIDE;
      m[ca] = (_Float16)((float)m[ca] - v0);
      m[ca + MT_STRIDE] = (_Float16)((float)m[ca + MT_STRIDE] - v1);
      m[ca + 2 * MT_STRIDE] = (_Float16)((float)m[ca + 2 * MT_STRIDE] - v2);
      m[cb] = (_Float16)((float)m[cb] + v0);
      m[cb + MT_STRIDE] = (_Float16)((float)m[cb + MT_STRIDE] + v1);
      m[cb + 2 * MT_STRIDE] = (_Float16)((float)m[cb + 2 * MT_STRIDE] + v2);
    }
  } else {
    // pair 208 = (20,18), pair 209 = (20,19)
    for (int r = tid - DIMD; r < DIMI; r += 256 - DIMD) {
      int at = r / 3, u = r - 3 * at;
      float v208 = (at == 20) ? pick3(Rdn2[208], u)
                 : (at == 18) ? -pick3(Rdn2[208], u) : 0.f;
      float v209 = (at == 20) ? pick3(Rdn2[209], u)
                 : (at == 19) ? -pick3(Rdn2[209], u) : 0.f;
      Gk[r][0] = (_Float16)v208;
      Gk[r][1] = (_Float16)v209;
    }
  }
  __syncthreads();   // MT + Gk ready

  // ---- MFMA: tile = A·M + G^T·b (K-slots 208..223 from Gk/MT) ----
  f32x4 acc0 = {0.f, 0.f, 0.f, 0.f}, acc1 = acc0, acc2 = acc0, acc3 = acc0;
  const int lane = tid & 63;
  const int nt = tid >> 6;
  const int ci = lane & 15;
  const int kOct = lane >> 4;
  {
    const _Float16* Ag = (const _Float16*)((const char*)ws + A_BYTE_OFF)
                         + (size_t)n * A_PER_N;
    const _Float16* aBase = Ag + ci * 224 + kOct * 8;
    const _Float16* mBase = &MT[(16 * nt + ci) * MT_STRIDE + kOct * 8];
#pragma unroll
    for (int kk = 0; kk < 7; ++kk) {
      f16x8 bf = *(const f16x8*)(mBase + kk * 32);
      f16x8 a0, a1, a2, a3;
      if (kk == 6 && kOct >= 2) {
        int off = (kOct - 2) * 8;
        a0 = *(const f16x8*)&Gk[ci][off];
        a1 = *(const f16x8*)&Gk[16 + ci][off];
        a2 = *(const f16x8*)&Gk[32 + ci][off];
        a3 = *(const f16x8*)&Gk[48 + ci][off];
      } else {
        a0 = *(const f16x8*)(aBase + kk * 32);
        a1 = *(const f16x8*)(aBase + 16 * 224 + kk * 32);
        a2 = *(const f16x8*)(aBase + 32 * 224 + kk * 32);
        a3 = *(const f16x8*)(aBase + 48 * 224 + kk * 32);
      }
      acc0 = __builtin_amdgcn_mfma_f32_16x16x32_f16(a0, bf, acc0, 0, 0, 0);
      acc1 = __builtin_amdgcn_mfma_f32_16x16x32_f16(a1, bf, acc1, 0, 0, 0);
      acc2 = __builtin_amdgcn_mfma_f32_16x16x32_f16(a2, bf, acc2, 0, 0, 0);
      acc3 = __builtin_amdgcn_mfma_f32_16x16x32_f16(a3, bf, acc3, 0, 0, 0);
    }
  }

  // ---- direct store: C/D layout col=16nt+ci, row=(kOct*4+r8)+16q; 64B segments ----
  {
    const int c = 16 * nt + ci;
    if (c < DIMI) {
      const size_t base = (size_t)n * DIMI * (NCOLS * DIMI) + (size_t)jc * DIMI;
      float* ob = out + base + c;
      const int rb = kOct * 4;
#pragma unroll
      for (int r8 = 0; r8 < 4; ++r8) {
        int r = rb + r8;
        ob[(size_t)r * (NCOLS * DIMI)] = acc0[r8];
        ob[(size_t)(16 + r) * (NCOLS * DIMI)] = acc1[r8];
        ob[(size_t)(32 + r) * (NCOLS * DIMI)] = acc2[r8];
        if (48 + r < DIMI) ob[(size_t)(48 + r) * (NCOLS * DIMI)] = acc3[r8];
      }
    }
  }
}

// ---------------- fallback CSR kernel (R12) ----------------
__global__ __launch_bounds__(256, 8) void gdml_main_csr(
    const float* __restrict__ R_desc, const float* __restrict__ R_d_desc,
    const int* __restrict__ j_idxs, const int* __restrict__ ws,
    float* __restrict__ out) {
  const int* perm    = ws + WS_PERM;
  const int* gtab    = ws + WS_GTAB;
  const int* entOff  = ws + WS_ENTOFF;
  const int* ents    = ws + WS_ENTS;
  const int* tileMap = ws + WS_TILEMAP;

  const int bid = blockIdx.x;
  const int jc = bid & 7;
  const int n = bid >> 3;
  const int tid = threadIdx.x;
  const int j = j_idxs[jc];

  __shared__ uint2 Rdn2[DIMD];
  __shared__ uint2 Rdj2[DIMD];
  __shared__ __align__(16) float GT[NPERM][64];
  __shared__ __align__(16) float bT[NPERM][64];
  __shared__ float c1s[NPERM], c2s[NPERM];
  __shared__ __align__(16) char uni[DIMI * 64 * 2];
  float* Rn = (float*)uni;
  float* Rj = Rn + DIMD;
  float* partial = Rj + DIMD;
  ushort* tileH = (ushort*)uni;

  for (int i = tid; i < DIMD; i += 256) {
    Rn[i] = R_desc[(size_t)n * DIMD + i];
    Rj[i] = R_desc[(size_t)j * DIMD + i];
  }
  if (tid < DIMD) {
    const float* gn = R_d_desc + (size_t)n * (DIMD * 3) + 3 * tid;
    const float* gj = R_d_desc + (size_t)j * (DIMD * 3) + 3 * tid;
    Rdn2[tid] = make_uint2(h16(gn[0]) | (h16(gn[1]) << 16), h16(gn[2]));
    Rdj2[tid] = make_uint2(h16(gj[0]) | (h16(gj[1]) << 16), h16(gj[2]));
  }
  __syncthreads();

  if (tid < 252) {
    int p = tid / 21, seg = tid % 21;
    const int* pp = &perm[p * DIMD + seg * 10];
    const float* rn = &Rn[seg * 10];
    float s = 0.f;
#pragma unroll
    for (int i = 0; i < 10; ++i) {
      float v = rn[i] - Rj[pp[i]];
      s += v * v;
    }
    partial[tid] = s;
  }
  __syncthreads();
  if (tid < NPERM) {
    float s = 0.f;
#pragma unroll
    for (int i = 0; i < 21; ++i) s += partial[tid * 21 + i];
    float nrm = sqrtf(5.0f) * sqrtf(s);
    float mat52 = expf(-nrm / SIGF) * (5.0f / (3.0f * SIGF * SIGF * SIGF * SIGF));
    c1s[tid] = 5.0f * mat52;
    c2s[tid] = (SIGF * SIGF + SIGF * nrm) * mat52;
  }
  __syncthreads();

  if (tid < NPERM * NATOM) {
    int p = tid / NATOM, at = tid % NATOM;
    const int* gt = &gtab[(p * NATOM + at) * 20];
    float g0 = 0, g1 = 0, g2 = 0, b0 = 0, b1 = 0, b2 = 0;
#pragma unroll
    for (int i = 0; i < 20; ++i) {
      int v = gt[i];
      int d = v & 511, tw = (v >> 9) & 511, pd = (v >> 18) & 511;
      unsigned sg = ((unsigned)(v & (1 << 27))) << 4;
      float fd = __uint_as_float(__float_as_uint(Rn[d] - Rj[pd]) ^ sg);
      float ftw = __uint_as_float(__float_as_uint(Rn[tw] - Rj[d]) ^ sg);
      uint2 rn = Rdn2[d];
      uint2 rj = Rdj2[d];
      g0 += uh(rn.x) * fd;  g1 += uh(rn.x >> 16) * fd;  g2 += uh(rn.y) * fd;
      b0 += uh(rj.x) * ftw; b1 += uh(rj.x >> 16) * ftw; b2 += uh(rj.y) * ftw;
    }
    float c1 = c1s[p];
    GT[p][3 * at + 0] = c1 * g0;
    GT[p][3 * at + 1] = c1 * g1;
    GT[p][3 * at + 2] = c1 * g2;
    bT[p][3 * at + 0] = b0;
    bT[p][3 * at + 1] = b1;
    bT[p][3 * at + 2] = b2;
  }
  __syncthreads();

  for (int s = 0; s < 2; ++s) {
    int rank;
    if (s == 0) { if (tid > 220) break; rank = tid; }
    else        { if (tid >= 220) break; rank = 440 - tid; }
    int q = tileMap[rank];
    int A = q / NATOM, B = q % NATOM;
    float acc[3][3];
#pragma unroll
    for (int c = 0; c < 3; ++c)
#pragma unroll
      for (int e = 0; e < 3; ++e) acc[c][e] = 0.f;

    int o0 = entOff[q], o1 = entOff[q + 1];
    for (int o = o0; o < o1; ++o) {
      int v = ents[o];
      int d8  = v & 0xFF8;
      int dd8 = (v >> 12) & 0xFF8;
      int p4  = (v >> 24) & 0x3C;
      unsigned sgn = ((unsigned)v & 0x40000000u) << 1;
      float c2 = __uint_as_float(
          __float_as_uint(*(const float*)((const char*)c2s + p4)) ^ sgn);
      uint2 rn = *(const uint2*)((const char*)Rdn2 + d8);
      uint2 rj = *(const uint2*)((const char*)Rdj2 + dd8);
      float nx = uh(rn.x), ny = uh(rn.x >> 16), nz = uh(rn.y);
      float w0 = c2 * uh(rj.x), w1 = c2 * uh(rj.x >> 16), w2 = c2 * uh(rj.y);
      acc[0][0] += nx * w0; acc[0][1] += nx * w1; acc[0][2] += nx * w2;
      acc[1][0] += ny * w0; acc[1][1] += ny * w1; acc[1][2] += ny * w2;
      acc[2][0] += nz * w0; acc[2][1] += nz * w1; acc[2][2] += nz * w2;
    }
#pragma unroll
    for (int cg = 0; cg < 3; ++cg) {
      int r = 3 * A + cg;
#pragma unroll
      for (int u = 0; u < 3; ++u)
        tileH[tswz(r, 3 * B + u)] = (ushort)h16(acc[cg][u]);
    }
  }
  __syncthreads();

  const size_t base = (size_t)n * DIMI * (NCOLS * DIMI) + (size_t)jc * DIMI;
  if (tid < 252) {
    int k = tid >> 2, ec = tid & 3;
    int e0 = ec * 16;
    const uint4* q0 = (const uint4*)&tileH[k * 64 + (((2 * ec) ^ k) & 7) * 8];
    const uint4* q1 = (const uint4*)&tileH[k * 64 + (((2 * ec + 1) ^ k) & 7) * 8];
    uint4 u0 = *q0, u1 = *q1;
    float acc[16];
    acc[0] = uh(u0.x);  acc[1] = uh(u0.x >> 16);
    acc[2] = uh(u0.y);  acc[3] = uh(u0.y >> 16);
    acc[4] = uh(u0.z);  acc[5] = uh(u0.z >> 16);
    acc[6] = uh(u0.w);  acc[7] = uh(u0.w >> 16);
    acc[8] = uh(u1.x);  acc[9] = uh(u1.x >> 16);
    acc[10] = uh(u1.y); acc[11] = uh(u1.y >> 16);
    acc[12] = uh(u1.z); acc[13] = uh(u1.z >> 16);
    acc[14] = uh(u1.w); acc[15] = uh(u1.w >> 16);
#pragma unroll
    for (int p = 0; p < NPERM; ++p) {
      float g = GT[p][k];
      const float4* bp = (const float4*)&bT[p][e0];
      float4 b0 = bp[0], b1 = bp[1], b2 = bp[2], b3 = bp[3];
      acc[0] += g * b0.x;  acc[1] += g * b0.y;  acc[2] += g * b0.z;  acc[3] += g * b0.w;
      acc[4] += g * b1.x;  acc[5] += g * b1.y;  acc[6] += g * b1.z;  acc[7] += g * b1.w;
      acc[8] += g * b2.x;  acc[9] += g * b2.y;  acc[10] += g * b2.z; acc[11] += g * b2.w;
      acc[12] += g * b3.x; acc[13] += g * b3.y; acc[14] += g * b3.z; acc[15] += g * b3.w;
    }
    float* op = out + base + (size_t)k * (NCOLS * DIMI) + e0;
    const int lim = DIMI - e0;
#pragma unroll
    for (int i = 0; i < 16; ++i)
      if (i < lim) op[i] = acc[i];
  }
}

extern "C" void kernel_launch(void* const* d_in, const int* in_sizes, int n_in,
                              void* d_out, int out_size, void* d_ws, size_t ws_size,
                              hipStream_t stream) {
  const float* R_desc = (const float*)d_in[0];
  const float* R_d_desc = (const float*)d_in[1];
  const int* tril = (const int*)d_in[2];
  const int* j_idxs = (const int*)d_in[3];
  float* out = (float*)d_out;
  int* ws = (int*)d_ws;

  const int wsBig = (ws_size >= WS_NEEDED) ? 1 : 0;
  hipLaunchKernelGGL(gdml_setup, dim3(1), dim3(512), 0, stream, tril, ws, wsBig);
  if (wsBig) {
    hipLaunchKernelGGL(build_A, dim3(NTRAIN), dim3(256), 0, stream, R_d_desc, ws);
    hipLaunchKernelGGL(gdml_main_mfma, dim3(NTRAIN * NCOLS), dim3(256), 0, stream,
                       R_desc, R_d_desc, j_idxs, ws, out);
  } else {
    hipLaunchKernelGGL(gdml_main_csr, dim3(NTRAIN * NCOLS), dim3(256), 0, stream,
                       R_desc, R_d_desc, j_idxs, ws, out);
  }
}

// Round 19
// 339.800 us; speedup vs baseline: 2.3488x; 1.0057x over previous
//
#include <hip/hip_runtime.h>
#include <hip/hip_fp16.h>
#include <math.h>

#define NTRAIN 2000
#define DIMD 210
#define DIMI 63
#define NPERM 12
#define NCOLS 8
#define NATOM 21
#define SIGF 10.0f

// ws layout (ints):
#define WS_PERM      0        // 2520
#define WS_PAIRROW   5040     // 210
#define WS_PAIRCOL   5250     // 210
#define WS_GTAB      6300     // 5040
#define WS_ENTOFF    11340    // 442
#define WS_ENTS      11782    // 10080
#define WS_TILEMAP   21862    // 441
#define WS_PERMAB    22304    // 2520 (ends 24824)
#define A_INT_OFF    25088
#define A_BYTE_OFF   (A_INT_OFF * 4)
#define A_PER_N      (64 * 224)
#define A_BYTES      ((size_t)NTRAIN * A_PER_N * 2)
#define WS_NEEDED    ((size_t)A_BYTE_OFF + A_BYTES)

typedef _Float16 f16x8 __attribute__((ext_vector_type(8)));
typedef float f32x4 __attribute__((ext_vector_type(4)));

// ---------------- setup (R15/R18 verbatim) ----------------
__global__ __launch_bounds__(512) void gdml_setup(const int* __restrict__ tril,
                                                  int* __restrict__ ws, int wsBig) {
  __shared__ int sPerm[NPERM * DIMD];
  __shared__ int sInv[NPERM * DIMD];
  __shared__ int sRow[DIMD], sCol[DIMD];
  __shared__ int sPairs[NATOM * 20], sNeg[NATOM * 20];
  __shared__ int sCnt[441];
  __shared__ int sScan[512];
  __shared__ int sOff[442];

  const int tid = threadIdx.x;

  for (int d = tid; d < DIMD; d += 512) {
    int a = 1;
    while ((a * (a + 1)) / 2 <= d) a++;
    sRow[d] = a;
    sCol[d] = d - (a * (a - 1)) / 2;
  }
  for (int idx = tid; idx < NPERM * DIMD; idx += 512) {
    int p = idx / DIMD, d = idx % DIMD;
    sPerm[idx] = tril[d * NPERM + p] % DIMD;
  }
  __syncthreads();
  for (int idx = tid; idx < NPERM * DIMD; idx += 512) {
    int p = idx / DIMD;
    sInv[p * DIMD + sPerm[idx]] = idx % DIMD;
  }
  if (tid < NATOM) {
    int t = tid, c = 0;
    for (int d = 0; d < DIMD; ++d) {
      if (sRow[d] == t)      { sPairs[t * 20 + c] = d; sNeg[t * 20 + c] = 0; c++; }
      else if (sCol[d] == t) { sPairs[t * 20 + c] = d; sNeg[t * 20 + c] = 1; c++; }
    }
  }
  __syncthreads();

  for (int idx = tid; idx < NPERM * DIMD; idx += 512) ws[WS_PERM + idx] = sPerm[idx];
  for (int d = tid; d < DIMD; d += 512) {
    ws[WS_PAIRROW + d] = sRow[d];
    ws[WS_PAIRCOL + d] = sCol[d];
  }
  for (int idx = tid; idx < NPERM * NATOM * 20; idx += 512) {
    int p = idx / (NATOM * 20);
    int r = idx % (NATOM * 20);
    int d = sPairs[r], neg = sNeg[r];
    int tw = sInv[p * DIMD + d];
    int pd = sPerm[p * DIMD + d];
    ws[WS_GTAB + idx] = d | (tw << 9) | (pd << 18) | (neg << 27);
  }
  if (wsBig) {
    for (int idx = tid; idx < NPERM * DIMD; idx += 512) {
      int dd = sPerm[idx];
      ws[WS_PERMAB + idx] = dd | (sRow[dd] << 8) | (sCol[dd] << 13);
    }
  }

  for (int q = tid; q < 441; q += 512) {
    int A = q / NATOM, B = q % NATOM, c = 0;
    for (int i = 0; i < 20; ++i) {
      int d = sPairs[A * 20 + i];
      for (int p = 0; p < NPERM; ++p) {
        int dd = sPerm[p * DIMD + d];
        c += (sRow[dd] == B) + (sCol[dd] == B);
      }
    }
    sCnt[q] = c;
  }
  __syncthreads();

  sScan[tid] = (tid < 441) ? sCnt[tid] : 0;
  __syncthreads();
  for (int s = 1; s < 512; s <<= 1) {
    int v = (tid >= s) ? sScan[tid - s] : 0;
    __syncthreads();
    sScan[tid] += v;
    __syncthreads();
  }
  if (tid == 0) sOff[0] = 0;
  if (tid < 441) sOff[tid + 1] = sScan[tid];
  __syncthreads();
  for (int q = tid; q < 442; q += 512) ws[WS_ENTOFF + q] = sOff[q];

  for (int q = tid; q < 441; q += 512) {
    int c = sCnt[q], r = 0;
    for (int q2 = 0; q2 < 441; ++q2) {
      int c2v = sCnt[q2];
      r += (c2v > c) || (c2v == c && q2 < q);
    }
    ws[WS_TILEMAP + r] = q;
  }

  for (int q = tid; q < 441; q += 512) {
    int A = q / NATOM, B = q % NATOM;
    int o = sOff[q];
    for (int i = 0; i < 20; ++i) {
      int d = sPairs[A * 20 + i];
      int negA = sNeg[A * 20 + i];
      for (int p = 0; p < NPERM; ++p) {
        int dd = sPerm[p * DIMD + d];
        int base = (d << 3) | (dd << 15) | (p << 26);
        if (sRow[dd] == B) ws[WS_ENTS + (o++)] = base | ((negA ^ 1) << 30);
        if (sCol[dd] == B) ws[WS_ENTS + (o++)] = base | (negA << 30);
      }
    }
  }
}

// -------- build A_n = RdnFull^T (fp16 [64][224]) — sparse fill --------
__global__ __launch_bounds__(256) void build_A(const float* __restrict__ R_d_desc,
                                               int* __restrict__ ws) {
  const int bid = blockIdx.x;
  const int n = (bid & 7) * (NTRAIN / 8) + (bid >> 3);  // XCD-affine
  const int* gtab = ws + WS_GTAB;
  _Float16* A = (_Float16*)((char*)ws + A_BYTE_OFF) + (size_t)n * A_PER_N;
  const float* rd = R_d_desc + (size_t)n * (DIMD * 3);
  const int tid = threadIdx.x;

  f16x8 z = {0, 0, 0, 0, 0, 0, 0, 0};
  for (int u = tid; u < 64 * 28; u += 256) ((f16x8*)A)[u] = z;
  __syncthreads();

  for (int u = tid; u < NATOM * 20; u += 256) {
    int v = gtab[u];            // p=0 rows
    int d = v & 511;
    float s = (v & (1 << 27)) ? -1.0f : 1.0f;
    int at = u / 20;
    A[(3 * at + 0) * 224 + d] = (_Float16)(s * rd[3 * d + 0]);
    A[(3 * at + 1) * 224 + d] = (_Float16)(s * rd[3 * d + 1]);
    A[(3 * at + 2) * 224 + d] = (_Float16)(s * rd[3 * d + 2]);
  }
}

__device__ inline unsigned h16(float f) {
  return (unsigned)__half_as_ushort(__float2half_rn(f));
}
__device__ inline float uh(unsigned u) {
  return __half2float(__ushort_as_half((unsigned short)(u & 0xFFFFu)));
}
__device__ inline int tswz(int r, int e) {
  return r * 64 + ((((e >> 3) ^ r) & 7) << 3) + (e & 7);
}
__device__ inline float pick3(uint2 v, int u) {
  return (u == 0) ? uh(v.x) : (u == 1) ? uh(v.x >> 16) : uh(v.y);
}

#define MT_STRIDE 232

// ---------------- MFMA main: fused norms, packed RnRj, pipelined MFMA ----------------
__global__ __launch_bounds__(256, 4) void gdml_main_mfma(
    const float* __restrict__ R_desc, const float* __restrict__ R_d_desc,
    const int* __restrict__ j_idxs, const int* __restrict__ ws,
    float* __restrict__ out) {
  const int* gtab   = ws + WS_GTAB;
  const int* permAB = ws + WS_PERMAB;

  const int bid = blockIdx.x;
  const int x = bid & 7;
  const int t = bid >> 3;
  const int n = x * (NTRAIN / 8) + (t >> 3);   // XCD-affinity
  const int jc = t & 7;
  const int tid = threadIdx.x;
  const int j = j_idxs[jc];

  __shared__ __align__(16) _Float16 MT[64 * MT_STRIDE]; // 29,696
  __shared__ uint2 Rdn2[DIMD];                        // 1,680
  __shared__ uint2 Rdj2[DIMD];                        // 1,680
  __shared__ __align__(16) _Float16 Gk[64][16];       // 2,048
  __shared__ float c1s[NPERM], c2s[NPERM];            // 96
  __shared__ float2 RnRj[DIMD];                       // 1,680 (packed Rn,Rj)
  __shared__ float partial[252];                      // 1,008
  // total ~37.9 KB -> 4 blocks/CU

  // ---- stage inputs + zero MT + zero Gk ----
  if (tid < DIMD) {
    RnRj[tid] = make_float2(R_desc[(size_t)n * DIMD + tid],
                            R_desc[(size_t)j * DIMD + tid]);
    const float* gn = R_d_desc + (size_t)n * (DIMD * 3) + 3 * tid;
    const float* gj = R_d_desc + (size_t)j * (DIMD * 3) + 3 * tid;
    Rdn2[tid] = make_uint2(h16(gn[0]) | (h16(gn[1]) << 16), h16(gn[2]));
    Rdj2[tid] = make_uint2(h16(gj[0]) | (h16(gj[1]) << 16), h16(gj[2]));
  }
  {
    float4 zf = make_float4(0.f, 0.f, 0.f, 0.f);
    float4* mz = (float4*)MT;
    for (int i = tid; i < 64 * MT_STRIDE * 2 / 16; i += 256) mz[i] = zf;
    f16x8 z8 = {0, 0, 0, 0, 0, 0, 0, 0};
    for (int i = tid; i < 128; i += 256) ((f16x8*)Gk)[i] = z8;
  }
  __syncthreads();

  // ---- b/G raw + fused norm accumulation (scaling deferred past reduce) ----
  float g0 = 0, g1 = 0, g2 = 0, b0 = 0, b1 = 0, b2 = 0;
  int bp = 0, bat = 0;
  if (tid < NPERM * NATOM) {
    bp = tid / NATOM; bat = tid - bp * NATOM;
    const int* gt = &gtab[(bp * NATOM + bat) * 20];
    float nacc = 0.f;
#pragma unroll
    for (int i = 0; i < 20; ++i) {
      int v = gt[i];
      int d = v & 511, tw = (v >> 9) & 511, pd = (v >> 18) & 511;
      unsigned sg = ((unsigned)(v & (1 << 27))) << 4;
      float2 rrd = RnRj[d];
      float diff_d = rrd.x - RnRj[pd].y;          // Rn[d] - Rj[perm_p[d]]
      float diff_tw = RnRj[tw].x - rrd.y;         // Rn[tw] - Rj[d]
      float fd = __uint_as_float(__float_as_uint(diff_d) ^ sg);
      float ftw = __uint_as_float(__float_as_uint(diff_tw) ^ sg);
      nacc += diff_d * diff_d;                    // each diff counted twice block-wide
      uint2 rn = Rdn2[d];
      uint2 rj = Rdj2[d];
      g0 += uh(rn.x) * fd;  g1 += uh(rn.x >> 16) * fd;  g2 += uh(rn.y) * fd;
      b0 += uh(rj.x) * ftw; b1 += uh(rj.x >> 16) * ftw; b2 += uh(rj.y) * ftw;
    }
    partial[tid] = nacc;
  }
  __syncthreads();

  // ---- reduce -> c1s, c2s (double-count corrected by /2) ----
  if (tid < NPERM) {
    float s = 0.f;
#pragma unroll
    for (int i = 0; i < 21; ++i) s += partial[tid * 21 + i];
    s *= 0.5f;
    float nrm = sqrtf(5.0f) * sqrtf(s);
    float mat52 = expf(-nrm / SIGF) * (5.0f / (3.0f * SIGF * SIGF * SIGF * SIGF));
    c1s[tid] = 5.0f * mat52;
    c2s[tid] = (SIGF * SIGF + SIGF * nrm) * mat52;
  }
  __syncthreads();

  // ---- write Gk/b-slots (scaled), M-build, Gk slots 0,1 ----
  if (tid < NPERM * NATOM) {
    float c1 = c1s[bp];
    Gk[3 * bat + 0][4 + bp] = (_Float16)(c1 * g0);
    Gk[3 * bat + 1][4 + bp] = (_Float16)(c1 * g1);
    Gk[3 * bat + 2][4 + bp] = (_Float16)(c1 * g2);
    MT[(3 * bat + 0) * MT_STRIDE + 212 + bp] = (_Float16)b0;
    MT[(3 * bat + 1) * MT_STRIDE + 212 + bp] = (_Float16)b1;
    MT[(3 * bat + 2) * MT_STRIDE + 212 + bp] = (_Float16)b2;
  }
  if (tid < DIMD) {
    int d = tid;
    _Float16* m = MT + d;
#pragma unroll
    for (int p = 0; p < NPERM; ++p) {
      int v = permAB[p * DIMD + d];
      int dd = v & 255, a = (v >> 8) & 31, b = (v >> 13) & 31;
      float c2 = c2s[p];
      uint2 rj = Rdj2[dd];
      float v0 = c2 * uh(rj.x), v1 = c2 * uh(rj.x >> 16), v2 = c2 * uh(rj.y);
      int ca = (3 * a) * MT_STRIDE, cb = (3 * b) * MT_STRIDE;
      m[ca] = (_Float16)((float)m[ca] - v0);
      m[ca + MT_STRIDE] = (_Float16)((float)m[ca + MT_STRIDE] - v1);
      m[ca + 2 * MT_STRIDE] = (_Float16)((float)m[ca + 2 * MT_STRIDE] - v2);
      m[cb] = (_Float16)((float)m[cb] + v0);
      m[cb + MT_STRIDE] = (_Float16)((float)m[cb + MT_STRIDE] + v1);
      m[cb + 2 * MT_STRIDE] = (_Float16)((float)m[cb + 2 * MT_STRIDE] + v2);
    }
  } else {
    // pair 208 = (20,18), pair 209 = (20,19)
    for (int r = tid - DIMD; r < DIMI; r += 256 - DIMD) {
      int at = r / 3, u = r - 3 * at;
      float v208 = (at == 20) ? pick3(Rdn2[208], u)
                 : (at == 18) ? -pick3(Rdn2[208], u) : 0.f;
      float v209 = (at == 20) ? pick3(Rdn2[209], u)
                 : (at == 19) ? -pick3(Rdn2[209], u) : 0.f;
      Gk[r][0] = (_Float16)v208;
      Gk[r][1] = (_Float16)v209;
    }
  }
  __syncthreads();   // MT + Gk ready

  // ---- MFMA: kk=0..5 pipelined clean loop; kk=6 peeled (Gk injection) ----
  f32x4 acc0 = {0.f, 0.f, 0.f, 0.f}, acc1 = acc0, acc2 = acc0, acc3 = acc0;
  const int lane = tid & 63;
  const int nt = tid >> 6;
  const int ci = lane & 15;
  const int kOct = lane >> 4;
  const _Float16* Ag = (const _Float16*)((const char*)ws + A_BYTE_OFF)
                       + (size_t)n * A_PER_N;
  const _Float16* aBase = Ag + ci * 224 + kOct * 8;
  const _Float16* mBase = &MT[(16 * nt + ci) * MT_STRIDE + kOct * 8];
  {
    f16x8 bf_c = *(const f16x8*)(mBase);
    f16x8 a0_c = *(const f16x8*)(aBase);
    f16x8 a1_c = *(const f16x8*)(aBase + 16 * 224);
    f16x8 a2_c = *(const f16x8*)(aBase + 32 * 224);
    f16x8 a3_c = *(const f16x8*)(aBase + 48 * 224);
#pragma unroll
    for (int kk = 0; kk < 6; ++kk) {
      f16x8 bf_n, a0_n, a1_n, a2_n, a3_n;
      if (kk < 5) {
        bf_n = *(const f16x8*)(mBase + (kk + 1) * 32);
        a0_n = *(const f16x8*)(aBase + (kk + 1) * 32);
        a1_n = *(const f16x8*)(aBase + 16 * 224 + (kk + 1) * 32);
        a2_n = *(const f16x8*)(aBase + 32 * 224 + (kk + 1) * 32);
        a3_n = *(const f16x8*)(aBase + 48 * 224 + (kk + 1) * 32);
      }
      acc0 = __builtin_amdgcn_mfma_f32_16x16x32_f16(a0_c, bf_c, acc0, 0, 0, 0);
      acc1 = __builtin_amdgcn_mfma_f32_16x16x32_f16(a1_c, bf_c, acc1, 0, 0, 0);
      acc2 = __builtin_amdgcn_mfma_f32_16x16x32_f16(a2_c, bf_c, acc2, 0, 0, 0);
      acc3 = __builtin_amdgcn_mfma_f32_16x16x32_f16(a3_c, bf_c, acc3, 0, 0, 0);
      if (kk < 5) {
        bf_c = bf_n; a0_c = a0_n; a1_c = a1_n; a2_c = a2_n; a3_c = a3_n;
      }
    }
    // kk = 6: K-slots 192..223. kOct<2 -> real A cols 192..207; kOct>=2 -> Gk (term1)
    f16x8 bf6 = *(const f16x8*)(mBase + 6 * 32);
    f16x8 a0, a1, a2, a3;
    if (kOct >= 2) {
      int off = (kOct - 2) * 8;
      a0 = *(const f16x8*)&Gk[ci][off];
      a1 = *(const f16x8*)&Gk[16 + ci][off];
      a2 = *(const f16x8*)&Gk[32 + ci][off];
      a3 = *(const f16x8*)&Gk[48 + ci][off];
    } else {
      a0 = *(const f16x8*)(aBase + 6 * 32);
      a1 = *(const f16x8*)(aBase + 16 * 224 + 6 * 32);
      a2 = *(const f16x8*)(aBase + 32 * 224 + 6 * 32);
      a3 = *(const f16x8*)(aBase + 48 * 224 + 6 * 32);
    }
    acc0 = __builtin_amdgcn_mfma_f32_16x16x32_f16(a0, bf6, acc0, 0, 0, 0);
    acc1 = __builtin_amdgcn_mfma_f32_16x16x32_f16(a1, bf6, acc1, 0, 0, 0);
    acc2 = __builtin_amdgcn_mfma_f32_16x16x32_f16(a2, bf6, acc2, 0, 0, 0);
    acc3 = __builtin_amdgcn_mfma_f32_16x16x32_f16(a3, bf6, acc3, 0, 0, 0);
  }

  // ---- direct store: C/D layout col=16nt+ci, row=(kOct*4+r8)+16q ----
  {
    const int c = 16 * nt + ci;
    if (c < DIMI) {
      const size_t base = (size_t)n * DIMI * (NCOLS * DIMI) + (size_t)jc * DIMI;
      float* ob = out + base + c;
      const int rb = kOct * 4;
#pragma unroll
      for (int r8 = 0; r8 < 4; ++r8) {
        int r = rb + r8;
        ob[(size_t)r * (NCOLS * DIMI)] = acc0[r8];
        ob[(size_t)(16 + r) * (NCOLS * DIMI)] = acc1[r8];
        ob[(size_t)(32 + r) * (NCOLS * DIMI)] = acc2[r8];
        if (48 + r < DIMI) ob[(size_t)(48 + r) * (NCOLS * DIMI)] = acc3[r8];
      }
    }
  }
}

// ---------------- fallback CSR kernel (R12) ----------------
__global__ __launch_bounds__(256, 8) void gdml_main_csr(
    const float* __restrict__ R_desc, const float* __restrict__ R_d_desc,
    const int* __restrict__ j_idxs, const int* __restrict__ ws,
    float* __restrict__ out) {
  const int* perm    = ws + WS_PERM;
  const int* gtab    = ws + WS_GTAB;
  const int* entOff  = ws + WS_ENTOFF;
  const int* ents    = ws + WS_ENTS;
  const int* tileMap = ws + WS_TILEMAP;

  const int bid = blockIdx.x;
  const int jc = bid & 7;
  const int n = bid >> 3;
  const int tid = threadIdx.x;
  const int j = j_idxs[jc];

  __shared__ uint2 Rdn2[DIMD];
  __shared__ uint2 Rdj2[DIMD];
  __shared__ __align__(16) float GT[NPERM][64];
  __shared__ __align__(16) float bT[NPERM][64];
  __shared__ float c1s[NPERM], c2s[NPERM];
  __shared__ __align__(16) char uni[DIMI * 64 * 2];
  float* Rn = (float*)uni;
  float* Rj = Rn + DIMD;
  float* partial = Rj + DIMD;
  ushort* tileH = (ushort*)uni;

  for (int i = tid; i < DIMD; i += 256) {
    Rn[i] = R_desc[(size_t)n * DIMD + i];
    Rj[i] = R_desc[(size_t)j * DIMD + i];
  }
  if (tid < DIMD) {
    const float* gn = R_d_desc + (size_t)n * (DIMD * 3) + 3 * tid;
    const float* gj = R_d_desc + (size_t)j * (DIMD * 3) + 3 * tid;
    Rdn2[tid] = make_uint2(h16(gn[0]) | (h16(gn[1]) << 16), h16(gn[2]));
    Rdj2[tid] = make_uint2(h16(gj[0]) | (h16(gj[1]) << 16), h16(gj[2]));
  }
  __syncthreads();

  if (tid < 252) {
    int p = tid / 21, seg = tid % 21;
    const int* pp = &perm[p * DIMD + seg * 10];
    const float* rn = &Rn[seg * 10];
    float s = 0.f;
#pragma unroll
    for (int i = 0; i < 10; ++i) {
      float v = rn[i] - Rj[pp[i]];
      s += v * v;
    }
    partial[tid] = s;
  }
  __syncthreads();
  if (tid < NPERM) {
    float s = 0.f;
#pragma unroll
    for (int i = 0; i < 21; ++i) s += partial[tid * 21 + i];
    float nrm = sqrtf(5.0f) * sqrtf(s);
    float mat52 = expf(-nrm / SIGF) * (5.0f / (3.0f * SIGF * SIGF * SIGF * SIGF));
    c1s[tid] = 5.0f * mat52;
    c2s[tid] = (SIGF * SIGF + SIGF * nrm) * mat52;
  }
  __syncthreads();

  if (tid < NPERM * NATOM) {
    int p = tid / NATOM, at = tid % NATOM;
    const int* gt = &gtab[(p * NATOM + at) * 20];
    float g0 = 0, g1 = 0, g2 = 0, b0 = 0, b1 = 0, b2 = 0;
#pragma unroll
    for (int i = 0; i < 20; ++i) {
      int v = gt[i];
      int d = v & 511, tw = (v >> 9) & 511, pd = (v >> 18) & 511;
      unsigned sg = ((unsigned)(v & (1 << 27))) << 4;
      float fd = __uint_as_float(__float_as_uint(Rn[d] - Rj[pd]) ^ sg);
      float ftw = __uint_as_float(__float_as_uint(Rn[tw] - Rj[d]) ^ sg);
      uint2 rn = Rdn2[d];
      uint2 rj = Rdj2[d];
      g0 += uh(rn.x) * fd;  g1 += uh(rn.x >> 16) * fd;  g2 += uh(rn.y) * fd;
      b0 += uh(rj.x) * ftw; b1 += uh(rj.x >> 16) * ftw; b2 += uh(rj.y) * ftw;
    }
    float c1 = c1s[p];
    GT[p][3 * at + 0] = c1 * g0;
    GT[p][3 * at + 1] = c1 * g1;
    GT[p][3 * at + 2] = c1 * g2;
    bT[p][3 * at + 0] = b0;
    bT[p][3 * at + 1] = b1;
    bT[p][3 * at + 2] = b2;
  }
  __syncthreads();

  for (int s = 0; s < 2; ++s) {
    int rank;
    if (s == 0) { if (tid > 220) break; rank = tid; }
    else        { if (tid >= 220) break; rank = 440 - tid; }
    int q = tileMap[rank];
    int A = q / NATOM, B = q % NATOM;
    float acc[3][3];
#pragma unroll
    for (int c = 0; c < 3; ++c)
#pragma unroll
      for (int e = 0; e < 3; ++e) acc[c][e] = 0.f;

    int o0 = entOff[q], o1 = entOff[q + 1];
    for (int o = o0; o < o1; ++o) {
      int v = ents[o];
      int d8  = v & 0xFF8;
      int dd8 = (v >> 12) & 0xFF8;
      int p4  = (v >> 24) & 0x3C;
      unsigned sgn = ((unsigned)v & 0x40000000u) << 1;
      float c2 = __uint_as_float(
          __float_as_uint(*(const float*)((const char*)c2s + p4)) ^ sgn);
      uint2 rn = *(const uint2*)((const char*)Rdn2 + d8);
      uint2 rj = *(const uint2*)((const char*)Rdj2 + dd8);
      float nx = uh(rn.x), ny = uh(rn.x >> 16), nz = uh(rn.y);
      float w0 = c2 * uh(rj.x), w1 = c2 * uh(rj.x >> 16), w2 = c2 * uh(rj.y);
      acc[0][0] += nx * w0; acc[0][1] += nx * w1; acc[0][2] += nx * w2;
      acc[1][0] += ny * w0; acc[1][1] += ny * w1; acc[1][2] += ny * w2;
      acc[2][0] += nz * w0; acc[2][1] += nz * w1; acc[2][2] += nz * w2;
    }
#pragma unroll
    for (int cg = 0; cg < 3; ++cg) {
      int r = 3 * A + cg;
#pragma unroll
      for (int u = 0; u < 3; ++u)
        tileH[tswz(r, 3 * B + u)] = (ushort)h16(acc[cg][u]);
    }
  }
  __syncthreads();

  const size_t base = (size_t)n * DIMI * (NCOLS * DIMI) + (size_t)jc * DIMI;
  if (tid < 252) {
    int k = tid >> 2, ec = tid & 3;
    int e0 = ec * 16;
    const uint4* q0 = (const uint4*)&tileH[k * 64 + (((2 * ec) ^ k) & 7) * 8];
    const uint4* q1 = (const uint4*)&tileH[k * 64 + (((2 * ec + 1) ^ k) & 7) * 8];
    uint4 u0 = *q0, u1 = *q1;
    float acc[16];
    acc[0] = uh(u0.x);  acc[1] = uh(u0.x >> 16);
    acc[2] = uh(u0.y);  acc[3] = uh(u0.y >> 16);
    acc[4] = uh(u0.z);  acc[5] = uh(u0.z >> 16);
    acc[6] = uh(u0.w);  acc[7] = uh(u0.w >> 16);
    acc[8] = uh(u1.x);  acc[9] = uh(u1.x >> 16);
    acc[10] = uh(u1.y); acc[11] = uh(u1.y >> 16);
    acc[12] = uh(u1.z); acc[13] = uh(u1.z >> 16);
    acc[14] = uh(u1.w); acc[15] = uh(u1.w >> 16);
#pragma unroll
    for (int p = 0; p < NPERM; ++p) {
      float g = GT[p][k];
      const float4* bp = (const float4*)&bT[p][e0];
      float4 b0 = bp[0], b1 = bp[1], b2 = bp[2], b3 = bp[3];
      acc[0] += g * b0.x;  acc[1] += g * b0.y;  acc[2] += g * b0.z;  acc[3] += g * b0.w;
      acc[4] += g * b1.x;  acc[5] += g * b1.y;  acc[6] += g * b1.z;  acc[7] += g * b1.w;
      acc[8] += g * b2.x;  acc[9] += g * b2.y;  acc[10] += g * b2.z; acc[11] += g * b2.w;
      acc[12] += g * b3.x; acc[13] += g * b3.y; acc[14] += g * b3.z; acc[15] += g * b3.w;
    }
    float* op = out + base + (size_t)k * (NCOLS * DIMI) + e0;
    const int lim = DIMI - e0;
#pragma unroll
    for (int i = 0; i < 16; ++i)
      if (i < lim) op[i] = acc[i];
  }
}

extern "C" void kernel_launch(void* const* d_in, const int* in_sizes, int n_in,
                              void* d_out, int out_size, void* d_ws, size_t ws_size,
                              hipStream_t stream) {
  const float* R_desc = (const float*)d_in[0];
  const float* R_d_desc = (const float*)d_in[1];
  const int* tril = (const int*)d_in[2];
  const int* j_idxs = (const int*)d_in[3];
  float* out = (float*)d_out;
  int* ws = (int*)d_ws;

  const int wsBig = (ws_size >= WS_NEEDED) ? 1 : 0;
  hipLaunchKernelGGL(gdml_setup, dim3(1), dim3(512), 0, stream, tril, ws, wsBig);
  if (wsBig) {
    hipLaunchKernelGGL(build_A, dim3(NTRAIN), dim3(256), 0, stream, R_d_desc, ws);
    hipLaunchKernelGGL(gdml_main_mfma, dim3(NTRAIN * NCOLS), dim3(256), 0, stream,
                       R_desc, R_d_desc, j_idxs, ws, out);
  } else {
    hipLaunchKernelGGL(gdml_main_csr, dim3(NTRAIN * NCOLS), dim3(256), 0, stream,
                       R_desc, R_d_desc, j_idxs, ws, out);
  }
}

// Round 20
// 281.536 us; speedup vs baseline: 2.8349x; 1.2069x over previous
//
#include <hip/hip_runtime.h>
#include <hip/hip_fp16.h>
#include <math.h>

#define NTRAIN 2000
#define DIMD 210
#define DIMI 63
#define NPERM 12
#define NCOLS 8
#define NATOM 21
#define SIGF 10.0f

// ws layout (ints):
#define WS_PERM      0        // 2520
#define WS_PAIRROW   5040     // 210
#define WS_PAIRCOL   5250     // 210
#define WS_GTAB      6300     // 5040
#define WS_ENTOFF    11340    // 442
#define WS_ENTS      11782    // 10080
#define WS_TILEMAP   21862    // 441
#define WS_PERMAB    22304    // 2520 (ends 24824)
#define A_INT_OFF    25088
#define A_BYTE_OFF   (A_INT_OFF * 4)
#define A_PER_N      (64 * 224)
#define A_BYTES      ((size_t)NTRAIN * A_PER_N * 2)
#define WS_NEEDED    ((size_t)A_BYTE_OFF + A_BYTES)

typedef _Float16 f16x8 __attribute__((ext_vector_type(8)));
typedef float f32x4 __attribute__((ext_vector_type(4)));

// ---------------- setup: fallback tables built ONLY when !wsBig ----------------
__global__ __launch_bounds__(512) void gdml_setup(const int* __restrict__ tril,
                                                  int* __restrict__ ws, int wsBig) {
  __shared__ int sPerm[NPERM * DIMD];
  __shared__ int sInv[NPERM * DIMD];
  __shared__ int sRow[DIMD], sCol[DIMD];
  __shared__ int sPairs[NATOM * 20], sNeg[NATOM * 20];
  __shared__ int sCnt[441];
  __shared__ int sScan[512];
  __shared__ int sOff[442];

  const int tid = threadIdx.x;

  for (int d = tid; d < DIMD; d += 512) {
    int a = 1;
    while ((a * (a + 1)) / 2 <= d) a++;
    sRow[d] = a;
    sCol[d] = d - (a * (a - 1)) / 2;
  }
  for (int idx = tid; idx < NPERM * DIMD; idx += 512) {
    int p = idx / DIMD, d = idx % DIMD;
    sPerm[idx] = tril[d * NPERM + p] % DIMD;
  }
  __syncthreads();
  for (int idx = tid; idx < NPERM * DIMD; idx += 512) {
    int p = idx / DIMD;
    sInv[p * DIMD + sPerm[idx]] = idx % DIMD;
  }
  if (tid < NATOM) {
    int t = tid, c = 0;
    for (int d = 0; d < DIMD; ++d) {
      if (sRow[d] == t)      { sPairs[t * 20 + c] = d; sNeg[t * 20 + c] = 0; c++; }
      else if (sCol[d] == t) { sPairs[t * 20 + c] = d; sNeg[t * 20 + c] = 1; c++; }
    }
  }
  __syncthreads();

  // gtab[(p*21+at)*20+i] = d | tw<<9 | pd<<18 | neg<<27  (needed by BOTH paths)
  for (int idx = tid; idx < NPERM * NATOM * 20; idx += 512) {
    int p = idx / (NATOM * 20);
    int r = idx % (NATOM * 20);
    int d = sPairs[r], neg = sNeg[r];
    int tw = sInv[p * DIMD + d];
    int pd = sPerm[p * DIMD + d];
    ws[WS_GTAB + idx] = d | (tw << 9) | (pd << 18) | (neg << 27);
  }

  if (wsBig) {
    // MFMA path: only permAB needed beyond gtab
    for (int idx = tid; idx < NPERM * DIMD; idx += 512) {
      int dd = sPerm[idx];
      ws[WS_PERMAB + idx] = dd | (sRow[dd] << 8) | (sCol[dd] << 13);
    }
    return;   // skip all fallback-only table construction (~50% of setup time)
  }

  // -------- fallback path only below --------
  for (int idx = tid; idx < NPERM * DIMD; idx += 512) ws[WS_PERM + idx] = sPerm[idx];

  for (int q = tid; q < 441; q += 512) {
    int A = q / NATOM, B = q % NATOM, c = 0;
    for (int i = 0; i < 20; ++i) {
      int d = sPairs[A * 20 + i];
      for (int p = 0; p < NPERM; ++p) {
        int dd = sPerm[p * DIMD + d];
        c += (sRow[dd] == B) + (sCol[dd] == B);
      }
    }
    sCnt[q] = c;
  }
  __syncthreads();

  sScan[tid] = (tid < 441) ? sCnt[tid] : 0;
  __syncthreads();
  for (int s = 1; s < 512; s <<= 1) {
    int v = (tid >= s) ? sScan[tid - s] : 0;
    __syncthreads();
    sScan[tid] += v;
    __syncthreads();
  }
  if (tid == 0) sOff[0] = 0;
  if (tid < 441) sOff[tid + 1] = sScan[tid];
  __syncthreads();
  for (int q = tid; q < 442; q += 512) ws[WS_ENTOFF + q] = sOff[q];

  for (int q = tid; q < 441; q += 512) {
    int c = sCnt[q], r = 0;
    for (int q2 = 0; q2 < 441; ++q2) {
      int c2v = sCnt[q2];
      r += (c2v > c) || (c2v == c && q2 < q);
    }
    ws[WS_TILEMAP + r] = q;
  }

  for (int q = tid; q < 441; q += 512) {
    int A = q / NATOM, B = q % NATOM;
    int o = sOff[q];
    for (int i = 0; i < 20; ++i) {
      int d = sPairs[A * 20 + i];
      int negA = sNeg[A * 20 + i];
      for (int p = 0; p < NPERM; ++p) {
        int dd = sPerm[p * DIMD + d];
        int base = (d << 3) | (dd << 15) | (p << 26);
        if (sRow[dd] == B) ws[WS_ENTS + (o++)] = base | ((negA ^ 1) << 30);
        if (sCol[dd] == B) ws[WS_ENTS + (o++)] = base | (negA << 30);
      }
    }
  }
}

// -------- build A_n = RdnFull^T (fp16 [64][224]) — sparse fill --------
__global__ __launch_bounds__(256) void build_A(const float* __restrict__ R_d_desc,
                                               int* __restrict__ ws) {
  const int bid = blockIdx.x;
  const int n = (bid & 7) * (NTRAIN / 8) + (bid >> 3);  // XCD-affine
  const int* gtab = ws + WS_GTAB;
  _Float16* A = (_Float16*)((char*)ws + A_BYTE_OFF) + (size_t)n * A_PER_N;
  const float* rd = R_d_desc + (size_t)n * (DIMD * 3);
  const int tid = threadIdx.x;

  f16x8 z = {0, 0, 0, 0, 0, 0, 0, 0};
  for (int u = tid; u < 64 * 28; u += 256) ((f16x8*)A)[u] = z;
  __syncthreads();

  for (int u = tid; u < NATOM * 20; u += 256) {
    int v = gtab[u];            // p=0 rows
    int d = v & 511;
    float s = (v & (1 << 27)) ? -1.0f : 1.0f;
    int at = u / 20;
    A[(3 * at + 0) * 224 + d] = (_Float16)(s * rd[3 * d + 0]);
    A[(3 * at + 1) * 224 + d] = (_Float16)(s * rd[3 * d + 1]);
    A[(3 * at + 2) * 224 + d] = (_Float16)(s * rd[3 * d + 2]);
  }
}

__device__ inline unsigned h16(float f) {
  return (unsigned)__half_as_ushort(__float2half_rn(f));
}
__device__ inline float uh(unsigned u) {
  return __half2float(__ushort_as_half((unsigned short)(u & 0xFFFFu)));
}
__device__ inline int tswz(int r, int e) {
  return r * 64 + ((((e >> 3) ^ r) & 7) << 3) + (e & 7);
}
__device__ inline float pick3(uint2 v, int u) {
  return (u == 0) ? uh(v.x) : (u == 1) ? uh(v.x >> 16) : uh(v.y);
}

#define MT_STRIDE 232

// ---------------- MFMA main (R19 verbatim — proven 268 us) ----------------
__global__ __launch_bounds__(256, 4) void gdml_main_mfma(
    const float* __restrict__ R_desc, const float* __restrict__ R_d_desc,
    const int* __restrict__ j_idxs, const int* __restrict__ ws,
    float* __restrict__ out) {
  const int* gtab   = ws + WS_GTAB;
  const int* permAB = ws + WS_PERMAB;

  const int bid = blockIdx.x;
  const int x = bid & 7;
  const int t = bid >> 3;
  const int n = x * (NTRAIN / 8) + (t >> 3);   // XCD-affinity
  const int jc = t & 7;
  const int tid = threadIdx.x;
  const int j = j_idxs[jc];

  __shared__ __align__(16) _Float16 MT[64 * MT_STRIDE]; // 29,696
  __shared__ uint2 Rdn2[DIMD];                        // 1,680
  __shared__ uint2 Rdj2[DIMD];                        // 1,680
  __shared__ __align__(16) _Float16 Gk[64][16];       // 2,048
  __shared__ float c1s[NPERM], c2s[NPERM];            // 96
  __shared__ float2 RnRj[DIMD];                       // 1,680
  __shared__ float partial[252];                      // 1,008
  // total ~37.9 KB -> 4 blocks/CU

  // ---- stage inputs + zero MT + zero Gk ----
  if (tid < DIMD) {
    RnRj[tid] = make_float2(R_desc[(size_t)n * DIMD + tid],
                            R_desc[(size_t)j * DIMD + tid]);
    const float* gn = R_d_desc + (size_t)n * (DIMD * 3) + 3 * tid;
    const float* gj = R_d_desc + (size_t)j * (DIMD * 3) + 3 * tid;
    Rdn2[tid] = make_uint2(h16(gn[0]) | (h16(gn[1]) << 16), h16(gn[2]));
    Rdj2[tid] = make_uint2(h16(gj[0]) | (h16(gj[1]) << 16), h16(gj[2]));
  }
  {
    float4 zf = make_float4(0.f, 0.f, 0.f, 0.f);
    float4* mz = (float4*)MT;
    for (int i = tid; i < 64 * MT_STRIDE * 2 / 16; i += 256) mz[i] = zf;
    f16x8 z8 = {0, 0, 0, 0, 0, 0, 0, 0};
    for (int i = tid; i < 128; i += 256) ((f16x8*)Gk)[i] = z8;
  }
  __syncthreads();

  // ---- b/G raw + fused norm accumulation ----
  float g0 = 0, g1 = 0, g2 = 0, b0 = 0, b1 = 0, b2 = 0;
  int bp = 0, bat = 0;
  if (tid < NPERM * NATOM) {
    bp = tid / NATOM; bat = tid - bp * NATOM;
    const int* gt = &gtab[(bp * NATOM + bat) * 20];
    float nacc = 0.f;
#pragma unroll
    for (int i = 0; i < 20; ++i) {
      int v = gt[i];
      int d = v & 511, tw = (v >> 9) & 511, pd = (v >> 18) & 511;
      unsigned sg = ((unsigned)(v & (1 << 27))) << 4;
      float2 rrd = RnRj[d];
      float diff_d = rrd.x - RnRj[pd].y;
      float diff_tw = RnRj[tw].x - rrd.y;
      float fd = __uint_as_float(__float_as_uint(diff_d) ^ sg);
      float ftw = __uint_as_float(__float_as_uint(diff_tw) ^ sg);
      nacc += diff_d * diff_d;
      uint2 rn = Rdn2[d];
      uint2 rj = Rdj2[d];
      g0 += uh(rn.x) * fd;  g1 += uh(rn.x >> 16) * fd;  g2 += uh(rn.y) * fd;
      b0 += uh(rj.x) * ftw; b1 += uh(rj.x >> 16) * ftw; b2 += uh(rj.y) * ftw;
    }
    partial[tid] = nacc;
  }
  __syncthreads();

  if (tid < NPERM) {
    float s = 0.f;
#pragma unroll
    for (int i = 0; i < 21; ++i) s += partial[tid * 21 + i];
    s *= 0.5f;
    float nrm = sqrtf(5.0f) * sqrtf(s);
    float mat52 = expf(-nrm / SIGF) * (5.0f / (3.0f * SIGF * SIGF * SIGF * SIGF));
    c1s[tid] = 5.0f * mat52;
    c2s[tid] = (SIGF * SIGF + SIGF * nrm) * mat52;
  }
  __syncthreads();

  if (tid < NPERM * NATOM) {
    float c1 = c1s[bp];
    Gk[3 * bat + 0][4 + bp] = (_Float16)(c1 * g0);
    Gk[3 * bat + 1][4 + bp] = (_Float16)(c1 * g1);
    Gk[3 * bat + 2][4 + bp] = (_Float16)(c1 * g2);
    MT[(3 * bat + 0) * MT_STRIDE + 212 + bp] = (_Float16)b0;
    MT[(3 * bat + 1) * MT_STRIDE + 212 + bp] = (_Float16)b1;
    MT[(3 * bat + 2) * MT_STRIDE + 212 + bp] = (_Float16)b2;
  }
  if (tid < DIMD) {
    int d = tid;
    _Float16* m = MT + d;
#pragma unroll
    for (int p = 0; p < NPERM; ++p) {
      int v = permAB[p * DIMD + d];
      int dd = v & 255, a = (v >> 8) & 31, b = (v >> 13) & 31;
      float c2 = c2s[p];
      uint2 rj = Rdj2[dd];
      float v0 = c2 * uh(rj.x), v1 = c2 * uh(rj.x >> 16), v2 = c2 * uh(rj.y);
      int ca = (3 * a) * MT_STRIDE, cb = (3 * b) * MT_STRIDE;
      m[ca] = (_Float16)((float)m[ca] - v0);
      m[ca + MT_STRIDE] = (_Float16)((float)m[ca + MT_STRIDE] - v1);
      m[ca + 2 * MT_STRIDE] = (_Float16)((float)m[ca + 2 * MT_STRIDE] - v2);
      m[cb] = (_Float16)((float)m[cb] + v0);
      m[cb + MT_STRIDE] = (_Float16)((float)m[cb + MT_STRIDE] + v1);
      m[cb + 2 * MT_STRIDE] = (_Float16)((float)m[cb + 2 * MT_STRIDE] + v2);
    }
  } else {
    for (int r = tid - DIMD; r < DIMI; r += 256 - DIMD) {
      int at = r / 3, u = r - 3 * at;
      float v208 = (at == 20) ? pick3(Rdn2[208], u)
                 : (at == 18) ? -pick3(Rdn2[208], u) : 0.f;
      float v209 = (at == 20) ? pick3(Rdn2[209], u)
                 : (at == 19) ? -pick3(Rdn2[209], u) : 0.f;
      Gk[r][0] = (_Float16)v208;
      Gk[r][1] = (_Float16)v209;
    }
  }
  __syncthreads();

  // ---- MFMA: kk=0..5 pipelined; kk=6 peeled (Gk injection) ----
  f32x4 acc0 = {0.f, 0.f, 0.f, 0.f}, acc1 = acc0, acc2 = acc0, acc3 = acc0;
  const int lane = tid & 63;
  const int nt = tid >> 6;
  const int ci = lane & 15;
  const int kOct = lane >> 4;
  const _Float16* Ag = (const _Float16*)((const char*)ws + A_BYTE_OFF)
                       + (size_t)n * A_PER_N;
  const _Float16* aBase = Ag + ci * 224 + kOct * 8;
  const _Float16* mBase = &MT[(16 * nt + ci) * MT_STRIDE + kOct * 8];
  {
    f16x8 bf_c = *(const f16x8*)(mBase);
    f16x8 a0_c = *(const f16x8*)(aBase);
    f16x8 a1_c = *(const f16x8*)(aBase + 16 * 224);
    f16x8 a2_c = *(const f16x8*)(aBase + 32 * 224);
    f16x8 a3_c = *(const f16x8*)(aBase + 48 * 224);
#pragma unroll
    for (int kk = 0; kk < 6; ++kk) {
      f16x8 bf_n, a0_n, a1_n, a2_n, a3_n;
      if (kk < 5) {
        bf_n = *(const f16x8*)(mBase + (kk + 1) * 32);
        a0_n = *(const f16x8*)(aBase + (kk + 1) * 32);
        a1_n = *(const f16x8*)(aBase + 16 * 224 + (kk + 1) * 32);
        a2_n = *(const f16x8*)(aBase + 32 * 224 + (kk + 1) * 32);
        a3_n = *(const f16x8*)(aBase + 48 * 224 + (kk + 1) * 32);
      }
      acc0 = __builtin_amdgcn_mfma_f32_16x16x32_f16(a0_c, bf_c, acc0, 0, 0, 0);
      acc1 = __builtin_amdgcn_mfma_f32_16x16x32_f16(a1_c, bf_c, acc1, 0, 0, 0);
      acc2 = __builtin_amdgcn_mfma_f32_16x16x32_f16(a2_c, bf_c, acc2, 0, 0, 0);
      acc3 = __builtin_amdgcn_mfma_f32_16x16x32_f16(a3_c, bf_c, acc3, 0, 0, 0);
      if (kk < 5) {
        bf_c = bf_n; a0_c = a0_n; a1_c = a1_n; a2_c = a2_n; a3_c = a3_n;
      }
    }
    f16x8 bf6 = *(const f16x8*)(mBase + 6 * 32);
    f16x8 a0, a1, a2, a3;
    if (kOct >= 2) {
      int off = (kOct - 2) * 8;
      a0 = *(const f16x8*)&Gk[ci][off];
      a1 = *(const f16x8*)&Gk[16 + ci][off];
      a2 = *(const f16x8*)&Gk[32 + ci][off];
      a3 = *(const f16x8*)&Gk[48 + ci][off];
    } else {
      a0 = *(const f16x8*)(aBase + 6 * 32);
      a1 = *(const f16x8*)(aBase + 16 * 224 + 6 * 32);
      a2 = *(const f16x8*)(aBase + 32 * 224 + 6 * 32);
      a3 = *(const f16x8*)(aBase + 48 * 224 + 6 * 32);
    }
    acc0 = __builtin_amdgcn_mfma_f32_16x16x32_f16(a0, bf6, acc0, 0, 0, 0);
    acc1 = __builtin_amdgcn_mfma_f32_16x16x32_f16(a1, bf6, acc1, 0, 0, 0);
    acc2 = __builtin_amdgcn_mfma_f32_16x16x32_f16(a2, bf6, acc2, 0, 0, 0);
    acc3 = __builtin_amdgcn_mfma_f32_16x16x32_f16(a3, bf6, acc3, 0, 0, 0);
  }

  // ---- direct store ----
  {
    const int c = 16 * nt + ci;
    if (c < DIMI) {
      const size_t base = (size_t)n * DIMI * (NCOLS * DIMI) + (size_t)jc * DIMI;
      float* ob = out + base + c;
      const int rb = kOct * 4;
#pragma unroll
      for (int r8 = 0; r8 < 4; ++r8) {
        int r = rb + r8;
        ob[(size_t)r * (NCOLS * DIMI)] = acc0[r8];
        ob[(size_t)(16 + r) * (NCOLS * DIMI)] = acc1[r8];
        ob[(size_t)(32 + r) * (NCOLS * DIMI)] = acc2[r8];
        if (48 + r < DIMI) ob[(size_t)(48 + r) * (NCOLS * DIMI)] = acc3[r8];
      }
    }
  }
}

// ---------------- fallback CSR kernel (R12) ----------------
__global__ __launch_bounds__(256, 8) void gdml_main_csr(
    const float* __restrict__ R_desc, const float* __restrict__ R_d_desc,
    const int* __restrict__ j_idxs, const int* __restrict__ ws,
    float* __restrict__ out) {
  const int* perm    = ws + WS_PERM;
  const int* gtab    = ws + WS_GTAB;
  const int* entOff  = ws + WS_ENTOFF;
  const int* ents    = ws + WS_ENTS;
  const int* tileMap = ws + WS_TILEMAP;

  const int bid = blockIdx.x;
  const int jc = bid & 7;
  const int n = bid >> 3;
  const int tid = threadIdx.x;
  const int j = j_idxs[jc];

  __shared__ uint2 Rdn2[DIMD];
  __shared__ uint2 Rdj2[DIMD];
  __shared__ __align__(16) float GT[NPERM][64];
  __shared__ __align__(16) float bT[NPERM][64];
  __shared__ float c1s[NPERM], c2s[NPERM];
  __shared__ __align__(16) char uni[DIMI * 64 * 2];
  float* Rn = (float*)uni;
  float* Rj = Rn + DIMD;
  float* partial = Rj + DIMD;
  ushort* tileH = (ushort*)uni;

  for (int i = tid; i < DIMD; i += 256) {
    Rn[i] = R_desc[(size_t)n * DIMD + i];
    Rj[i] = R_desc[(size_t)j * DIMD + i];
  }
  if (tid < DIMD) {
    const float* gn = R_d_desc + (size_t)n * (DIMD * 3) + 3 * tid;
    const float* gj = R_d_desc + (size_t)j * (DIMD * 3) + 3 * tid;
    Rdn2[tid] = make_uint2(h16(gn[0]) | (h16(gn[1]) << 16), h16(gn[2]));
    Rdj2[tid] = make_uint2(h16(gj[0]) | (h16(gj[1]) << 16), h16(gj[2]));
  }
  __syncthreads();

  if (tid < 252) {
    int p = tid / 21, seg = tid % 21;
    const int* pp = &perm[p * DIMD + seg * 10];
    const float* rn = &Rn[seg * 10];
    float s = 0.f;
#pragma unroll
    for (int i = 0; i < 10; ++i) {
      float v = rn[i] - Rj[pp[i]];
      s += v * v;
    }
    partial[tid] = s;
  }
  __syncthreads();
  if (tid < NPERM) {
    float s = 0.f;
#pragma unroll
    for (int i = 0; i < 21; ++i) s += partial[tid * 21 + i];
    float nrm = sqrtf(5.0f) * sqrtf(s);
    float mat52 = expf(-nrm / SIGF) * (5.0f / (3.0f * SIGF * SIGF * SIGF * SIGF));
    c1s[tid] = 5.0f * mat52;
    c2s[tid] = (SIGF * SIGF + SIGF * nrm) * mat52;
  }
  __syncthreads();

  if (tid < NPERM * NATOM) {
    int p = tid / NATOM, at = tid % NATOM;
    const int* gt = &gtab[(p * NATOM + at) * 20];
    float g0 = 0, g1 = 0, g2 = 0, b0 = 0, b1 = 0, b2 = 0;
#pragma unroll
    for (int i = 0; i < 20; ++i) {
      int v = gt[i];
      int d = v & 511, tw = (v >> 9) & 511, pd = (v >> 18) & 511;
      unsigned sg = ((unsigned)(v & (1 << 27))) << 4;
      float fd = __uint_as_float(__float_as_uint(Rn[d] - Rj[pd]) ^ sg);
      float ftw = __uint_as_float(__float_as_uint(Rn[tw] - Rj[d]) ^ sg);
      uint2 rn = Rdn2[d];
      uint2 rj = Rdj2[d];
      g0 += uh(rn.x) * fd;  g1 += uh(rn.x >> 16) * fd;  g2 += uh(rn.y) * fd;
      b0 += uh(rj.x) * ftw; b1 += uh(rj.x >> 16) * ftw; b2 += uh(rj.y) * ftw;
    }
    float c1 = c1s[p];
    GT[p][3 * at + 0] = c1 * g0;
    GT[p][3 * at + 1] = c1 * g1;
    GT[p][3 * at + 2] = c1 * g2;
    bT[p][3 * at + 0] = b0;
    bT[p][3 * at + 1] = b1;
    bT[p][3 * at + 2] = b2;
  }
  __syncthreads();

  for (int s = 0; s < 2; ++s) {
    int rank;
    if (s == 0) { if (tid > 220) break; rank = tid; }
    else        { if (tid >= 220) break; rank = 440 - tid; }
    int q = tileMap[rank];
    int A = q / NATOM, B = q % NATOM;
    float acc[3][3];
#pragma unroll
    for (int c = 0; c < 3; ++c)
#pragma unroll
      for (int e = 0; e < 3; ++e) acc[c][e] = 0.f;

    int o0 = entOff[q], o1 = entOff[q + 1];
    for (int o = o0; o < o1; ++o) {
      int v = ents[o];
      int d8  = v & 0xFF8;
      int dd8 = (v >> 12) & 0xFF8;
      int p4  = (v >> 24) & 0x3C;
      unsigned sgn = ((unsigned)v & 0x40000000u) << 1;
      float c2 = __uint_as_float(
          __float_as_uint(*(const float*)((const char*)c2s + p4)) ^ sgn);
      uint2 rn = *(const uint2*)((const char*)Rdn2 + d8);
      uint2 rj = *(const uint2*)((const char*)Rdj2 + dd8);
      float nx = uh(rn.x), ny = uh(rn.x >> 16), nz = uh(rn.y);
      float w0 = c2 * uh(rj.x), w1 = c2 * uh(rj.x >> 16), w2 = c2 * uh(rj.y);
      acc[0][0] += nx * w0; acc[0][1] += nx * w1; acc[0][2] += nx * w2;
      acc[1][0] += ny * w0; acc[1][1] += ny * w1; acc[1][2] += ny * w2;
      acc[2][0] += nz * w0; acc[2][1] += nz * w1; acc[2][2] += nz * w2;
    }
#pragma unroll
    for (int cg = 0; cg < 3; ++cg) {
      int r = 3 * A + cg;
#pragma unroll
      for (int u = 0; u < 3; ++u)
        tileH[tswz(r, 3 * B + u)] = (ushort)h16(acc[cg][u]);
    }
  }
  __syncthreads();

  const size_t base = (size_t)n * DIMI * (NCOLS * DIMI) + (size_t)jc * DIMI;
  if (tid < 252) {
    int k = tid >> 2, ec = tid & 3;
    int e0 = ec * 16;
    const uint4* q0 = (const uint4*)&tileH[k * 64 + (((2 * ec) ^ k) & 7) * 8];
    const uint4* q1 = (const uint4*)&tileH[k * 64 + (((2 * ec + 1) ^ k) & 7) * 8];
    uint4 u0 = *q0, u1 = *q1;
    float acc[16];
    acc[0] = uh(u0.x);  acc[1] = uh(u0.x >> 16);
    acc[2] = uh(u0.y);  acc[3] = uh(u0.y >> 16);
    acc[4] = uh(u0.z);  acc[5] = uh(u0.z >> 16);
    acc[6] = uh(u0.w);  acc[7] = uh(u0.w >> 16);
    acc[8] = uh(u1.x);  acc[9] = uh(u1.x >> 16);
    acc[10] = uh(u1.y); acc[11] = uh(u1.y >> 16);
    acc[12] = uh(u1.z); acc[13] = uh(u1.z >> 16);
    acc[14] = uh(u1.w); acc[15] = uh(u1.w >> 16);
#pragma unroll
    for (int p = 0; p < NPERM; ++p) {
      float g = GT[p][k];
      const float4* bp = (const float4*)&bT[p][e0];
      float4 b0 = bp[0], b1 = bp[1], b2 = bp[2], b3 = bp[3];
      acc[0] += g * b0.x;  acc[1] += g * b0.y;  acc[2] += g * b0.z;  acc[3] += g * b0.w;
      acc[4] += g * b1.x;  acc[5] += g * b1.y;  acc[6] += g * b1.z;  acc[7] += g * b1.w;
      acc[8] += g * b2.x;  acc[9] += g * b2.y;  acc[10] += g * b2.z; acc[11] += g * b2.w;
      acc[12] += g * b3.x; acc[13] += g * b3.y; acc[14] += g * b3.z; acc[15] += g * b3.w;
    }
    float* op = out + base + (size_t)k * (NCOLS * DIMI) + e0;
    const int lim = DIMI - e0;
#pragma unroll
    for (int i = 0; i < 16; ++i)
      if (i < lim) op[i] = acc[i];
  }
}

extern "C" void kernel_launch(void* const* d_in, const int* in_sizes, int n_in,
                              void* d_out, int out_size, void* d_ws, size_t ws_size,
                              hipStream_t stream) {
  const float* R_desc = (const float*)d_in[0];
  const float* R_d_desc = (const float*)d_in[1];
  const int* tril = (const int*)d_in[2];
  const int* j_idxs = (const int*)d_in[3];
  float* out = (float*)d_out;
  int* ws = (int*)d_ws;

  const int wsBig = (ws_size >= WS_NEEDED) ? 1 : 0;
  hipLaunchKernelGGL(gdml_setup, dim3(1), dim3(512), 0, stream, tril, ws, wsBig);
  if (wsBig) {
    hipLaunchKernelGGL(build_A, dim3(NTRAIN), dim3(256), 0, stream, R_d_desc, ws);
    hipLaunchKernelGGL(gdml_main_mfma, dim3(NTRAIN * NCOLS), dim3(256), 0, stream,
                       R_desc, R_d_desc, j_idxs, ws, out);
  } else {
    hipLaunchKernelGGL(gdml_main_csr, dim3(NTRAIN * NCOLS), dim3(256), 0, stream,
                       R_desc, R_d_desc, j_idxs, ws, out);
  }
}